// Round 3
// baseline (739.147 us; speedup 1.0000x reference)
//
#include <hip/hip_runtime.h>
#include <hip/hip_cooperative_groups.h>
#include <math.h>

namespace cg = cooperative_groups;

#define N_NODES 20000
#define M_PAD   20032            // 64-row padded for MFMA row tiles
#define E_EDGES 640000
#define ET (E_EDGES + N_NODES)   // edges + self loops
#define IN_CH 256
#define D1 128                   // H1*C1 = 8*16
#define D2 256                   // H2*C2 = 1*256
#define BPAIRS 4096
#define NEG 0.2f
#define LOG2E 1.4426950408889634f

#define COOP_BLOCKS 512                            // 2 blocks/CU x 256 CU, guaranteed resident
#define WT_BLOCKS 32                               // 4 matrices x 8 64x64 tiles
#define ZC_BLOCKS 20                               // fallback: zero count
#define XCONV_BLOCKS (M_PAD * IN_CH / 4 / 4 / 256) // 1252 (ILP-4, fallback)
#define RANK_BLOCKS  ((ET + 255) / 256)            // 2579
#define SCAT_BLOCKS  ((ET + 255) / 256)

#define G1X (M_PAD / 64)             // 313
#define G1_BLOCKS (G1X * (D1 / 64))  // 626
#define G2_TILES  (G1X * (D2 / 64))  // 1252

#if __has_builtin(__builtin_amdgcn_exp2f)
#define EXP2F(x) __builtin_amdgcn_exp2f(x)
#else
#define EXP2F(x) exp2f(x)
#endif

typedef __bf16 bf16x8 __attribute__((ext_vector_type(8)));
typedef float  f32x4  __attribute__((ext_vector_type(4)));
typedef float  f32x2  __attribute__((ext_vector_type(2)));
typedef unsigned short u16x4 __attribute__((ext_vector_type(4)));

__device__ __forceinline__ unsigned short f2b(float f) {
    unsigned int u = __float_as_uint(f);
    unsigned int r = u + 0x7FFFu + ((u >> 16) & 1u);   // RNE
    return (unsigned short)(r >> 16);
}
__device__ __forceinline__ unsigned char f2f8(float f) {
    return (unsigned char)(__builtin_amdgcn_cvt_pk_fp8_f32(f, f, 0, false) & 0xFF);
}
template <bool HI>
__device__ __forceinline__ f32x2 f8up2(unsigned int u) {
    return __builtin_amdgcn_cvt_pk_f32_fp8((int)u, HI);
}
__device__ __forceinline__ f32x2 up2(unsigned int u) {
    f32x2 r;
    r.x = __uint_as_float(u << 16);
    r.y = __uint_as_float(u & 0xFFFF0000u);
    return r;
}
__device__ __forceinline__ f32x2 lrelu2(f32x2 s) {
    return __builtin_elementwise_max(s, s * NEG);
}
__device__ __forceinline__ float lrelu(float s) { return fmaxf(s, NEG * s); }

__device__ __forceinline__ void unpack8(uint4 u, float* v) {
    v[0] = __uint_as_float(u.x << 16); v[1] = __uint_as_float(u.x & 0xFFFF0000u);
    v[2] = __uint_as_float(u.y << 16); v[3] = __uint_as_float(u.y & 0xFFFF0000u);
    v[4] = __uint_as_float(u.z << 16); v[5] = __uint_as_float(u.z & 0xFFFF0000u);
    v[6] = __uint_as_float(u.w << 16); v[7] = __uint_as_float(u.w & 0xFFFF0000u);
}
__device__ __forceinline__ void unpack8_f8(uint2 u, float* v) {
    f32x2 a = f8up2<false>(u.x), b = f8up2<true>(u.x);
    f32x2 c = f8up2<false>(u.y), d = f8up2<true>(u.y);
    v[0] = a.x; v[1] = a.y; v[2] = b.x; v[3] = b.y;
    v[4] = c.x; v[5] = c.y; v[6] = d.x; v[7] = d.y;
}

// ---------------- shared device pieces ----------------

// W [K x N] -> Wt [N x K] via 64x64 LDS tile (t = 0..31)
__device__ __forceinline__ void dev_wt_tile(int t,
        const float* __restrict__ Wl1, const float* __restrict__ Wr1,
        const float* __restrict__ Wl2, const float* __restrict__ Wr2,
        unsigned short* __restrict__ wt1l, unsigned short* __restrict__ wt1r,
        unsigned short* __restrict__ wt2l, unsigned short* __restrict__ wt2r,
        unsigned short* tile) {                     // 64 x 65 bf16 LDS
    int m = t >> 3;
    int tt = t & 7;
    const float* W;
    unsigned short* Wt;
    int K, N;
    if (m == 0)      { W = Wl1; Wt = wt1l; K = IN_CH; N = D1; }
    else if (m == 1) { W = Wr1; Wt = wt1r; K = IN_CH; N = D1; }
    else if (m == 2) { W = Wl2; Wt = wt2l; K = D1; N = D2; }
    else             { W = Wr2; Wt = wt2r; K = D1; N = D2; }
    int ntn = N >> 6;
    int k0 = (tt / ntn) << 6;
    int n0 = (tt % ntn) << 6;
    int c = threadIdx.x & 63;
    int rr = threadIdx.x >> 6;
#pragma unroll
    for (int ch = 0; ch < 16; ch++) {
        int row = rr * 16 + ch;
        tile[row * 65 + c] = f2b(W[(size_t)(k0 + row) * N + n0 + c]);
    }
    __syncthreads();
#pragma unroll
    for (int ch = 0; ch < 16; ch++) {
        int n = rr * 16 + ch;
        Wt[(size_t)(n0 + n) * K + k0 + c] = tile[c * 65 + n];
    }
}

// one float4-group of the x -> bf16 conversion (zero row padding)
__device__ __forceinline__ void dev_xconv(int qi,
        const float* __restrict__ gnn_x, unsigned short* __restrict__ xb) {
    int e0 = qi * 4;
    int row = e0 >> 8;             // / IN_CH
    u16x4 o;
    if (row < N_NODES) {
        f32x4 v = __builtin_nontemporal_load((const f32x4*)(gnn_x + e0));
        o.x = f2b(v.x); o.y = f2b(v.y); o.z = f2b(v.z); o.w = f2b(v.w);
    } else {
        o.x = o.y = o.z = o.w = 0;
    }
    *(u16x4*)(xb + e0) = o;
}

// 256-thread two-pass scan of count[0..N_NODES) -> exclusive offsets
__device__ __forceinline__ void scan256(const int* __restrict__ count,
                                        int* __restrict__ offsets,
                                        int* wbuf) {   // >= 8 ints LDS
    const int PER = 79;            // 256*79 = 20224 >= 20000
    int t = threadIdx.x;
    int base = t * PER;
    int sum = 0;
#pragma unroll 8
    for (int i = 0; i < PER; i++) {
        int idx = base + i;
        if (idx < N_NODES) sum += count[idx];
    }
    int lane = t & 63, wave = t >> 6;
    int s = sum;
#pragma unroll
    for (int off = 1; off < 64; off <<= 1) {
        int x = __shfl_up(s, off);
        if (lane >= off) s += x;
    }
    int* wsum = wbuf;
    int* wpre = wbuf + 4;
    if (lane == 63) wsum[wave] = s;
    __syncthreads();
    if (t == 0) {
        int acc = 0;
        for (int w = 0; w < 4; w++) { wpre[w] = acc; acc += wsum[w]; }
    }
    __syncthreads();
    int excl = wpre[wave] + (s - sum);
    if (t == 255) offsets[N_NODES] = excl + sum;   // grand total == ET
    int run = excl;
#pragma unroll 8
    for (int i = 0; i < PER; i++) {
        int idx = base + i;
        if (idx < N_NODES) { offsets[idx] = run; run += count[idx]; }
    }
}

// dual GEMM 64x64 tile; B loaded inside k-loop (moderate VGPR)
template <int K>
__device__ __forceinline__ void dual_gemm_tile(
        const unsigned short* __restrict__ A,
        const unsigned short* __restrict__ Wtl,
        const unsigned short* __restrict__ Wtr,
        const float* __restrict__ bl, const float* __restrict__ br,
        unsigned char* __restrict__ Yl, unsigned short* __restrict__ Yr,
        int M, int NOUT, int bx, int by) {
    const int NK = K / 32;
    int wave = threadIdx.x >> 6;
    int lane = threadIdx.x & 63;
    int row0 = bx * 64;
    int col0 = (by * 4 + wave) * 16;
    int rsub = lane & 15;
    int koff = (lane >> 4) * 8;

    const unsigned short* ap  = A   + (size_t)(row0 + rsub) * K + koff;
    const unsigned short* bpl = Wtl + (size_t)(col0 + rsub) * K + koff;
    const unsigned short* bpr = Wtr + (size_t)(col0 + rsub) * K + koff;

    f32x4 l0 = {0.f, 0.f, 0.f, 0.f};
    f32x4 l1 = l0, l2 = l0, l3 = l0, r0 = l0, r1 = l0, r2 = l0, r3 = l0;

#pragma unroll
    for (int kb = 0; kb < NK; kb++) {
        int off = kb * 32;
        bf16x8 bfl = *(const bf16x8*)(bpl + off);
        bf16x8 bfr = *(const bf16x8*)(bpr + off);
        bf16x8 a0 = *(const bf16x8*)(ap + off);
        bf16x8 a1 = *(const bf16x8*)(ap + 16 * K + off);
        bf16x8 a2 = *(const bf16x8*)(ap + 32 * K + off);
        bf16x8 a3 = *(const bf16x8*)(ap + 48 * K + off);
        l0 = __builtin_amdgcn_mfma_f32_16x16x32_bf16(a0, bfl, l0, 0, 0, 0);
        r0 = __builtin_amdgcn_mfma_f32_16x16x32_bf16(a0, bfr, r0, 0, 0, 0);
        l1 = __builtin_amdgcn_mfma_f32_16x16x32_bf16(a1, bfl, l1, 0, 0, 0);
        r1 = __builtin_amdgcn_mfma_f32_16x16x32_bf16(a1, bfr, r1, 0, 0, 0);
        l2 = __builtin_amdgcn_mfma_f32_16x16x32_bf16(a2, bfl, l2, 0, 0, 0);
        r2 = __builtin_amdgcn_mfma_f32_16x16x32_bf16(a2, bfr, r2, 0, 0, 0);
        l3 = __builtin_amdgcn_mfma_f32_16x16x32_bf16(a3, bfl, l3, 0, 0, 0);
        r3 = __builtin_amdgcn_mfma_f32_16x16x32_bf16(a3, bfr, r3, 0, 0, 0);
    }

    int colg = col0 + rsub;
    float bvl = bl[colg];
    float bvr = br[colg];
    int rbase = row0 + (lane >> 4) * 4;
#pragma unroll
    for (int t = 0; t < 4; t++) {
        f32x4 al = (t == 0) ? l0 : (t == 1) ? l1 : (t == 2) ? l2 : l3;
        f32x4 ar = (t == 0) ? r0 : (t == 1) ? r1 : (t == 2) ? r2 : r3;
#pragma unroll
        for (int r = 0; r < 4; r++) {
            int row = rbase + t * 16 + r;
            if (row < M) {
                Yl[(size_t)row * NOUT + colg] = f2f8(al[r] + bvl);
                Yr[(size_t)row * NOUT + colg] = f2b(ar[r] + bvr);
            }
        }
    }
}

// layer-1 aggregation for one dst row (one wave; quarter-wave/edge, prefetch-2)
__device__ __forceinline__ void agg1_unit(
        const unsigned char* __restrict__ xl1, const unsigned short* __restrict__ xr1,
        const float* __restrict__ att1, const float* __restrict__ bias1,
        const int* __restrict__ offsets, const int* __restrict__ sorted_src,
        unsigned short* __restrict__ x1, int dst, int lane) {
    int q = lane >> 4;                 // quarter 0..3
    int ql = lane & 15;
    int c0 = ql * 8;                   // channel index (8 ch/lane)
    if (dst >= N_NODES) {              // zero pad rows for the next GEMM
        if (q == 0) {
            uint4 z; z.x = z.y = z.z = z.w = 0;
            *(uint4*)(x1 + (size_t)dst * D1 + c0) = z;
        }
        return;
    }
    uint4 xu = *(const uint4*)(xr1 + (size_t)dst * D1 + c0);
    f32x2 xr[4] = {up2(xu.x), up2(xu.y), up2(xu.z), up2(xu.w)};
    float4 aa0 = *(const float4*)(att1 + c0);
    float4 aa1 = *(const float4*)(att1 + c0 + 4);
    f32x2 att[4];
    att[0].x = aa0.x * LOG2E; att[0].y = aa0.y * LOG2E;
    att[1].x = aa0.z * LOG2E; att[1].y = aa0.w * LOG2E;
    att[2].x = aa1.x * LOG2E; att[2].y = aa1.y * LOG2E;
    att[3].x = aa1.z * LOG2E; att[3].y = aa1.w * LOG2E;

    int beg = offsets[dst], end = offsets[dst + 1];
    const unsigned char* base = xl1 + c0;

    float l = 0.f;
    f32x2 acc[4] = {{0.f,0.f},{0.f,0.f},{0.f,0.f},{0.f,0.f}};

    int i = beg;
    int s0 = sorted_src[min(i + q, end - 1)];
    uint2 g0 = *(const uint2*)(base + (size_t)s0 * D1);
    bool more1 = (i + 4) < end;
    uint2 g1;
    if (more1) {
        int s1 = sorted_src[min(i + 4 + q, end - 1)];
        g1 = *(const uint2*)(base + (size_t)s1 * D1);
    }
    while (true) {
        bool more2 = (i + 8) < end;
        uint2 g2;
        if (more2) {
            int s2 = sorted_src[min(i + 8 + q, end - 1)];
            g2 = *(const uint2*)(base + (size_t)s2 * D1);
        }
        bool act = (i + q) < end;
        f32x2 v0 = f8up2<false>(g0.x), v1 = f8up2<true>(g0.x);
        f32x2 v2 = f8up2<false>(g0.y), v3 = f8up2<true>(g0.y);
        f32x2 p2 = att[0] * lrelu2(v0 + xr[0]);
        p2 += att[1] * lrelu2(v1 + xr[1]);
        p2 += att[2] * lrelu2(v2 + xr[2]);
        p2 += att[3] * lrelu2(v3 + xr[3]);
        float p = p2.x + p2.y;
        p += __shfl_xor(p, 1);          // head reduce (2 lanes/head)
        float w = act ? EXP2F(p) : 0.f;
        l += w;
        acc[0] += w * v0; acc[1] += w * v1; acc[2] += w * v2; acc[3] += w * v3;
        if (!more1) break;
        i += 4;
        g0 = g1; g1 = g2; more1 = more2;
    }
    l += __shfl_xor(l, 16);
    l += __shfl_xor(l, 32);
#pragma unroll
    for (int j = 0; j < 4; j++) {
        f32x2 t;
        t.x = __shfl_xor(acc[j].x, 16); t.y = __shfl_xor(acc[j].y, 16);
        acc[j] += t;
        t.x = __shfl_xor(acc[j].x, 32); t.y = __shfl_xor(acc[j].y, 32);
        acc[j] += t;
    }
    if (q == 0) {
        float inv = 1.f / l;
        float4 bb0 = *(const float4*)(bias1 + c0);
        float4 bb1 = *(const float4*)(bias1 + c0 + 4);
        unsigned short o[8];
        o[0] = f2b(fmaxf(acc[0].x * inv + bb0.x, 0.f));
        o[1] = f2b(fmaxf(acc[0].y * inv + bb0.y, 0.f));
        o[2] = f2b(fmaxf(acc[1].x * inv + bb0.z, 0.f));
        o[3] = f2b(fmaxf(acc[1].y * inv + bb0.w, 0.f));
        o[4] = f2b(fmaxf(acc[2].x * inv + bb1.x, 0.f));
        o[5] = f2b(fmaxf(acc[2].y * inv + bb1.y, 0.f));
        o[6] = f2b(fmaxf(acc[3].x * inv + bb1.z, 0.f));
        o[7] = f2b(fmaxf(acc[3].y * inv + bb1.w, 0.f));
        uint4 ov;
        ov.x = (unsigned int)o[0] | ((unsigned int)o[1] << 16);
        ov.y = (unsigned int)o[2] | ((unsigned int)o[3] << 16);
        ov.z = (unsigned int)o[4] | ((unsigned int)o[5] << 16);
        ov.w = (unsigned int)o[6] | ((unsigned int)o[7] << 16);
        *(uint4*)(x1 + (size_t)dst * D1 + c0) = ov;
    }
}

// layer-2 aggregation + classifier for one pair (whole 256-thread block)
struct Agg2S {
    float x2row[2][D2];     // 2 KB
    float mrg[2][32][9];    // 2.25 KB
    float part[4];
    int stride_s;
};

__device__ __forceinline__ void agg2_pair(
        const unsigned char* __restrict__ xl2, const unsigned short* __restrict__ xr2,
        const float* __restrict__ att2, const float* __restrict__ bias2,
        const int* __restrict__ offsets, const int* __restrict__ sorted_src,
        const float* __restrict__ vanilla_x,
        const float* __restrict__ Wc, const float* __restrict__ bc,
        float* __restrict__ out, int b, int a1, int a2, Agg2S* S) {
    int t = threadIdx.x;
    int wave = t >> 6;
    int d = wave >> 1;
    int ww = wave & 1;
    int lane = t & 63;
    int half = lane >> 5;
    int hl = lane & 31;
    int c0 = hl * 8;
    int dst = d ? a2 : a1;

    float xr[8], att[8];
    unpack8(*(const uint4*)(xr2 + (size_t)dst * D2 + c0), xr);
#pragma unroll
    for (int j = 0; j < 8; j++) att[j] = att2[c0 + j] * LOG2E;
    int beg = offsets[dst], end = offsets[dst + 1];
    const unsigned char* base = xl2 + c0;

    float l = 0.f;
    float acc[8];
#pragma unroll
    for (int j = 0; j < 8; j++) acc[j] = 0.f;

    int sub = 2 * ww + half;           // edge slot 0..3
    int i = beg;
    int s0 = sorted_src[min(i + sub, end - 1)];
    uint2 g0 = *(const uint2*)(base + (size_t)s0 * D2);
    bool more1 = (i + 4) < end;
    uint2 g1;
    if (more1) {
        int s1 = sorted_src[min(i + 4 + sub, end - 1)];
        g1 = *(const uint2*)(base + (size_t)s1 * D2);
    }
    while (true) {
        bool more2 = (i + 8) < end;
        uint2 g2;
        if (more2) {
            int s2 = sorted_src[min(i + 8 + sub, end - 1)];
            g2 = *(const uint2*)(base + (size_t)s2 * D2);
        }
        bool act = (i + sub) < end;
        float v[8];
        unpack8_f8(g0, v);
        float p = 0.f;
#pragma unroll
        for (int j = 0; j < 8; j++) p = fmaf(att[j], lrelu(v[j] + xr[j]), p);
        p += __shfl_xor(p, 1);
        p += __shfl_xor(p, 2);
        p += __shfl_xor(p, 4);
        p += __shfl_xor(p, 8);
        p += __shfl_xor(p, 16);
        float w = act ? EXP2F(p) : 0.f;
        l += w;
#pragma unroll
        for (int j = 0; j < 8; j++) acc[j] += w * v[j];
        if (!more1) break;
        i += 4;
        g0 = g1; g1 = g2; more1 = more2;
    }
    l += __shfl_xor(l, 32);
#pragma unroll
    for (int j = 0; j < 8; j++) acc[j] += __shfl_xor(acc[j], 32);
    if (ww == 1 && half == 0) {
        S->mrg[d][hl][0] = l;
#pragma unroll
        for (int j = 0; j < 8; j++) S->mrg[d][hl][1 + j] = acc[j];
    }
    __syncthreads();
    if (ww == 0 && half == 0) {
        l += S->mrg[d][hl][0];
#pragma unroll
        for (int j = 0; j < 8; j++) acc[j] += S->mrg[d][hl][1 + j];
        float inv = 1.f / l;
#pragma unroll
        for (int j = 0; j < 8; j++)
            S->x2row[d][c0 + j] = acc[j] * inv + bias2[c0 + j];
    }
    __syncthreads();

    float s = vanilla_x[(size_t)a1 * IN_CH + t] * Wc[t]
            + vanilla_x[(size_t)a2 * IN_CH + t] * Wc[IN_CH + t]
            + S->x2row[0][t] * Wc[2 * IN_CH + t]
            + S->x2row[1][t] * Wc[3 * IN_CH + t];
    s += __shfl_xor(s, 1);
    s += __shfl_xor(s, 2);
    s += __shfl_xor(s, 4);
    s += __shfl_xor(s, 8);
    s += __shfl_xor(s, 16);
    s += __shfl_xor(s, 32);
    if (lane == 0) S->part[wave] = s;
    __syncthreads();
    if (t == 0) out[b] = S->part[0] + S->part[1] + S->part[2] + S->part[3] + bc[0];
}

// ---------------- cooperative mega-kernel ----------------

struct Params {
    const float* gnn_x; const float* vanilla_x;
    const int* edge_src; const int* edge_dst;
    const int* a1_raw; const int* a2_raw;
    const float* Wl1; const float* bl1; const float* Wr1; const float* br1;
    const float* att1; const float* bias1;
    const float* Wl2; const float* bl2; const float* Wr2; const float* br2;
    const float* att2; const float* bias2;
    const float* Wc; const float* bc;
    float* out;
    unsigned short* xb; unsigned short* x1b;
    unsigned char* xl1b; unsigned short* xr1b;
    unsigned char* xl2b; unsigned short* xr2b;
    unsigned short* wt1l; unsigned short* wt1r;
    unsigned short* wt2l; unsigned short* wt2r;
    int* count; int* offsets; int* rank; int* sorted_src;
};

// launch_bounds(256,2): VGPR cap 256 (no spill at ~110-170 actual),
// guarantees 2 blocks/CU residency -> COOP_BLOCKS=512 co-resident.
__global__ __launch_bounds__(256, 2) void mega_kernel(Params P) {
    cg::grid_group grid = cg::this_grid();
    __shared__ __align__(16) char smem_raw[8448];   // Wt tile / scan buf / Agg2S
    const int bid = blockIdx.x, tid = threadIdx.x, NB = gridDim.x;
    const int NT = NB * 256;
    const int g = bid * 256 + tid;

    // ---- P0: zero count + W^T transpose + x->bf16 convert ----
    for (int q = g; q < N_NODES / 4; q += NT) {
        int4 z; z.x = z.y = z.z = z.w = 0;
        ((int4*)P.count)[q] = z;
    }
    if (bid < WT_BLOCKS)
        dev_wt_tile(bid, P.Wl1, P.Wr1, P.Wl2, P.Wr2,
                    P.wt1l, P.wt1r, P.wt2l, P.wt2r, (unsigned short*)smem_raw);
    {
        const int NQ = M_PAD * IN_CH / 4;
        for (int qi = g; qi < NQ; qi += NT) dev_xconv(qi, P.gnn_x, P.xb);
    }
    grid.sync();

    // ---- P1: rank (atomics) overlapped with layer-1 dual GEMM ----
    for (int e = g; e < ET; e += NT) {
        int dst = (e < E_EDGES) ? P.edge_dst[e] : (e - E_EDGES);
        P.rank[e] = atomicAdd(&P.count[dst], 1);
    }
    for (int t = bid; t < G1_BLOCKS; t += NB)
        dual_gemm_tile<IN_CH>(P.xb, P.wt1l, P.wt1r, P.bl1, P.br1,
                              P.xl1b, P.xr1b, N_NODES, D1, t % G1X, t / G1X);
    grid.sync();

    // ---- P2: CSR scan (block 0 only) ----
    if (bid == 0) scan256(P.count, P.offsets, (int*)smem_raw);
    grid.sync();

    // ---- P3: scatter sorted_src ----
    for (int e = g; e < ET; e += NT) {
        int dst = (e < E_EDGES) ? P.edge_dst[e] : (e - E_EDGES);
        int src = (e < E_EDGES) ? P.edge_src[e] : (e - E_EDGES);
        P.sorted_src[P.offsets[dst] + P.rank[e]] = src;
    }
    grid.sync();

    // ---- P4: layer-1 aggregation (one dst per wave) ----
    {
        int wave = tid >> 6, lane = tid & 63;
        for (int dst = bid * 4 + wave; dst < M_PAD; dst += NB * 4)
            agg1_unit(P.xl1b, P.xr1b, P.att1, P.bias1,
                      P.offsets, P.sorted_src, P.x1b, dst, lane);
    }
    grid.sync();

    // ---- P5: layer-2 dual GEMM ----
    for (int t = bid; t < G2_TILES; t += NB)
        dual_gemm_tile<D1>(P.x1b, P.wt2l, P.wt2r, P.bl2, P.br2,
                           P.xl2b, P.xr2b, N_NODES, D2, t % G1X, t / G1X);
    grid.sync();

    // ---- P6: layer-2 aggregation + classifier (one pair per block) ----
    {
        Agg2S* S = (Agg2S*)smem_raw;
        if (tid < 64) {
            bool z = (tid < 31) ? (P.a1_raw[1 + 2 * tid] == 0) : true;
            unsigned long long m = __ballot(z);
            if (tid == 0) S->stride_s = (m == ~0ull) ? 2 : 1;
        }
        __syncthreads();
        int stride = S->stride_s;
        for (int b = bid; b < BPAIRS; b += NB) {
            int a1 = P.a1_raw[(long)b * stride];
            int a2 = P.a2_raw[(long)b * stride];
            agg2_pair(P.xl2b, P.xr2b, P.att2, P.bias2, P.offsets, P.sorted_src,
                      P.vanilla_x, P.Wc, P.bc, P.out, b, a1, a2, S);
            __syncthreads();
        }
    }
}

// ---------------- fallback (non-cooperative) kernels ----------------

__global__ __launch_bounds__(256) void prep_kernel_fb(
        const float* __restrict__ gnn_x,
        const float* __restrict__ Wl1, const float* __restrict__ Wr1,
        const float* __restrict__ Wl2, const float* __restrict__ Wr2,
        unsigned short* __restrict__ xb,
        unsigned short* __restrict__ wt1l, unsigned short* __restrict__ wt1r,
        unsigned short* __restrict__ wt2l, unsigned short* __restrict__ wt2r,
        int* __restrict__ count) {
    __shared__ __align__(16) unsigned short tile[64 * 65];
    int bid = blockIdx.x;
    if (bid < ZC_BLOCKS) {
        int q = bid * 256 + threadIdx.x;
        if (q < N_NODES / 4) {
            int4 z; z.x = z.y = z.z = z.w = 0;
            ((int4*)count)[q] = z;
        }
    } else if (bid < ZC_BLOCKS + WT_BLOCKS) {
        dev_wt_tile(bid - ZC_BLOCKS, Wl1, Wr1, Wl2, Wr2,
                    wt1l, wt1r, wt2l, wt2r, tile);
    } else {
        int tid = (bid - ZC_BLOCKS - WT_BLOCKS) * 256 + threadIdx.x;
        const int NQ = M_PAD * IN_CH / 4;
        int q0 = tid * 4;
#pragma unroll
        for (int j = 0; j < 4; j++) {
            int qi = q0 + j;
            if (qi >= NQ) break;
            dev_xconv(qi, gnn_x, xb);
        }
    }
}

__global__ __launch_bounds__(256) void rank_kernel_fb(
        const int* __restrict__ edge_dst,
        int* __restrict__ count, int* __restrict__ rank) {
    int e = blockIdx.x * 256 + threadIdx.x;
    if (e >= ET) return;
    int dst = (e < E_EDGES) ? edge_dst[e] : (e - E_EDGES);
    rank[e] = atomicAdd(&count[dst], 1);
}

__global__ __launch_bounds__(256) void scan_kernel_fb(const int* __restrict__ count,
                                                     int* __restrict__ offsets) {
    __shared__ int wbuf[8];
    scan256(count, offsets, wbuf);
}

__global__ __launch_bounds__(256) void gemm1_scatter_kernel_fb(
        const unsigned short* __restrict__ A,
        const unsigned short* __restrict__ Wtl,
        const unsigned short* __restrict__ Wtr,
        const float* __restrict__ bl, const float* __restrict__ br,
        unsigned char* __restrict__ Yl, unsigned short* __restrict__ Yr,
        const int* __restrict__ edge_src, const int* __restrict__ edge_dst,
        const int* __restrict__ rank, const int* __restrict__ offsets,
        int* __restrict__ sorted_src) {
    int bid = blockIdx.x;
    if (bid < G1_BLOCKS) {
        dual_gemm_tile<IN_CH>(A, Wtl, Wtr, bl, br, Yl, Yr,
                              N_NODES, D1, bid % G1X, bid / G1X);
    } else {
        int e = (bid - G1_BLOCKS) * 256 + threadIdx.x;
        if (e >= ET) return;
        int dst = (e < E_EDGES) ? edge_dst[e] : (e - E_EDGES);
        int src = (e < E_EDGES) ? edge_src[e] : (e - E_EDGES);
        sorted_src[offsets[dst] + rank[e]] = src;
    }
}

__global__ __launch_bounds__(256) void aggregate1_kernel_fb(
        const unsigned char* __restrict__ xl1, const unsigned short* __restrict__ xr1,
        const float* __restrict__ att1, const float* __restrict__ bias1,
        const int* __restrict__ offsets, const int* __restrict__ sorted_src,
        unsigned short* __restrict__ x1) {
    int dst = blockIdx.x * 4 + (threadIdx.x >> 6);
    if (dst >= M_PAD) return;
    agg1_unit(xl1, xr1, att1, bias1, offsets, sorted_src, x1, dst, threadIdx.x & 63);
}

template <int K>
__global__ __launch_bounds__(256) void dual_gemm_kernel_fb(
        const unsigned short* __restrict__ A,
        const unsigned short* __restrict__ Wtl,
        const unsigned short* __restrict__ Wtr,
        const float* __restrict__ bl, const float* __restrict__ br,
        unsigned char* __restrict__ Yl, unsigned short* __restrict__ Yr,
        int M, int NOUT) {
    dual_gemm_tile<K>(A, Wtl, Wtr, bl, br, Yl, Yr, M, NOUT, blockIdx.x, blockIdx.y);
}

__global__ __launch_bounds__(256) void agg2_classifier_kernel_fb(
        const unsigned char* __restrict__ xl2, const unsigned short* __restrict__ xr2,
        const float* __restrict__ att2, const float* __restrict__ bias2,
        const int* __restrict__ offsets, const int* __restrict__ sorted_src,
        const float* __restrict__ vanilla_x,
        const int* __restrict__ a1_raw, const int* __restrict__ a2_raw,
        const float* __restrict__ Wc, const float* __restrict__ bc,
        float* __restrict__ out) {
    __shared__ __align__(16) char smem_raw[sizeof(Agg2S)];
    Agg2S* S = (Agg2S*)smem_raw;
    int t = threadIdx.x;
    if (t < 64) {
        bool z = (t < 31) ? (a1_raw[1 + 2 * t] == 0) : true;
        unsigned long long m = __ballot(z);
        if (t == 0) S->stride_s = (m == ~0ull) ? 2 : 1;
    }
    __syncthreads();
    int stride = S->stride_s;
    int b = blockIdx.x;
    int a1 = a1_raw[(long)b * stride];
    int a2 = a2_raw[(long)b * stride];
    agg2_pair(xl2, xr2, att2, bias2, offsets, sorted_src,
              vanilla_x, Wc, bc, out, b, a1, a2, S);
}

// ---------------- launch ----------------

extern "C" void kernel_launch(void* const* d_in, const int* in_sizes, int n_in,
                              void* d_out, int out_size, void* d_ws, size_t ws_size,
                              hipStream_t stream) {
    const float* gnn_x     = (const float*)d_in[0];
    const float* vanilla_x = (const float*)d_in[1];
    const int*   edge_src  = (const int*)d_in[2];
    const int*   edge_dst  = (const int*)d_in[3];
    const int*   a1_idx    = (const int*)d_in[4];
    const int*   a2_idx    = (const int*)d_in[5];
    const float* Wl1   = (const float*)d_in[6];
    const float* bl1   = (const float*)d_in[7];
    const float* Wr1   = (const float*)d_in[8];
    const float* br1   = (const float*)d_in[9];
    const float* att1  = (const float*)d_in[10];
    const float* bias1 = (const float*)d_in[11];
    const float* Wl2   = (const float*)d_in[12];
    const float* bl2   = (const float*)d_in[13];
    const float* Wr2   = (const float*)d_in[14];
    const float* br2   = (const float*)d_in[15];
    const float* att2  = (const float*)d_in[16];
    const float* bias2 = (const float*)d_in[17];
    const float* Wc    = (const float*)d_in[18];
    const float* bc    = (const float*)d_in[19];
    float* out = (float*)d_out;

    // workspace layout (~44 MB)
    char* p = (char*)d_ws;
    unsigned short* xb   = (unsigned short*)p; p += (size_t)M_PAD * IN_CH * 2;
    unsigned short* x1b  = (unsigned short*)p; p += (size_t)M_PAD * D1 * 2;
    unsigned char*  xl1b = (unsigned char*)p;  p += (size_t)N_NODES * D1;      // fp8
    unsigned short* xr1b = (unsigned short*)p; p += (size_t)N_NODES * D1 * 2;
    unsigned char*  xl2b = (unsigned char*)p;  p += (size_t)N_NODES * D2;      // fp8
    unsigned short* xr2b = (unsigned short*)p; p += (size_t)N_NODES * D2 * 2;
    unsigned short* wt1l = (unsigned short*)p; p += (size_t)D1 * IN_CH * 2;
    unsigned short* wt1r = (unsigned short*)p; p += (size_t)D1 * IN_CH * 2;
    unsigned short* wt2l = (unsigned short*)p; p += (size_t)D2 * D1 * 2;
    unsigned short* wt2r = (unsigned short*)p; p += (size_t)D2 * D1 * 2;
    int* count      = (int*)p; p += (size_t)N_NODES * 4;
    int* offsets    = (int*)p; p += (size_t)(N_NODES + 4) * 4;
    int* rank       = (int*)p; p += (size_t)ET * 4;
    int* sorted_src = (int*)p; p += (size_t)ET * 4;

    // ---- try cooperative mega-kernel (no device queries; fixed safe grid) ----
    Params prm;
    prm.gnn_x = gnn_x; prm.vanilla_x = vanilla_x;
    prm.edge_src = edge_src; prm.edge_dst = edge_dst;
    prm.a1_raw = a1_idx; prm.a2_raw = a2_idx;
    prm.Wl1 = Wl1; prm.bl1 = bl1; prm.Wr1 = Wr1; prm.br1 = br1;
    prm.att1 = att1; prm.bias1 = bias1;
    prm.Wl2 = Wl2; prm.bl2 = bl2; prm.Wr2 = Wr2; prm.br2 = br2;
    prm.att2 = att2; prm.bias2 = bias2;
    prm.Wc = Wc; prm.bc = bc; prm.out = out;
    prm.xb = xb; prm.x1b = x1b;
    prm.xl1b = xl1b; prm.xr1b = xr1b; prm.xl2b = xl2b; prm.xr2b = xr2b;
    prm.wt1l = wt1l; prm.wt1r = wt1r; prm.wt2l = wt2l; prm.wt2r = wt2r;
    prm.count = count; prm.offsets = offsets;
    prm.rank = rank; prm.sorted_src = sorted_src;
    void* args[] = { (void*)&prm };
    if (hipLaunchCooperativeKernel(mega_kernel, dim3(COOP_BLOCKS), dim3(256),
                                   args, 0, stream) == hipSuccess)
        return;

    // ---- fallback: 7-dispatch pipeline ----
    prep_kernel_fb<<<ZC_BLOCKS + WT_BLOCKS + XCONV_BLOCKS, 256, 0, stream>>>(
        gnn_x, Wl1, Wr1, Wl2, Wr2, xb, wt1l, wt1r, wt2l, wt2r, count);
    rank_kernel_fb<<<RANK_BLOCKS, 256, 0, stream>>>(edge_dst, count, rank);
    scan_kernel_fb<<<1, 256, 0, stream>>>(count, offsets);
    gemm1_scatter_kernel_fb<<<G1_BLOCKS + SCAT_BLOCKS, 256, 0, stream>>>(
        xb, wt1l, wt1r, bl1, br1, xl1b, xr1b,
        edge_src, edge_dst, rank, offsets, sorted_src);
    aggregate1_kernel_fb<<<M_PAD / 4, 256, 0, stream>>>(
        xl1b, xr1b, att1, bias1, offsets, sorted_src, x1b);
    dual_gemm_kernel_fb<D1><<<dim3(G1X, D2 / 64), 256, 0, stream>>>(
        x1b, wt2l, wt2r, bl2, br2, xl2b, xr2b, N_NODES, D2);
    agg2_classifier_kernel_fb<<<BPAIRS, 256, 0, stream>>>(
        xl2b, xr2b, att2, bias2, offsets, sorted_src,
        vanilla_x, a1_idx, a2_idx, Wc, bc, out);
}

// Round 4
// 352.291 us; speedup vs baseline: 2.0981x; 2.0981x over previous
//
#include <hip/hip_runtime.h>
#include <math.h>

#define N_NODES 20000
#define M_PAD   20032            // 64-row padded for MFMA row tiles
#define E_EDGES 640000
#define ET (E_EDGES + N_NODES)   // edges + self loops
#define IN_CH 256
#define D1 128                   // H1*C1 = 8*16
#define D2 256                   // H2*C2 = 1*256
#define BPAIRS 4096
#define NEG 0.2f
#define LOG2E 1.4426950408889634f

#define ZERO_BLOCKS 20                             // 20*256*4 ints = 20480 (count+done)
#define WT_BLOCKS   32                             // 4 matrices x 8 64x64 tiles
#define XCONV_BLOCKS (M_PAD * IN_CH / 4 / 4 / 256) // 1252 (ILP-4)
#define RANK_BLOCKS  ((ET + 255) / 256)            // 2579
#define FRONT_BLOCKS (RANK_BLOCKS + WT_BLOCKS + XCONV_BLOCKS)

#define G1X (M_PAD / 64)          // 313
#define G1Y (D1 / 64)             // 2
#define G1_BLOCKS (G1X * G1Y)     // 626
#define SCAT_BLOCKS ((ET + 255) / 256)  // 2579

#if __has_builtin(__builtin_amdgcn_exp2f)
#define EXP2F(x) __builtin_amdgcn_exp2f(x)
#else
#define EXP2F(x) exp2f(x)
#endif

typedef __bf16 bf16x8 __attribute__((ext_vector_type(8)));
typedef float  f32x4  __attribute__((ext_vector_type(4)));
typedef float  f32x2  __attribute__((ext_vector_type(2)));
typedef unsigned short u16x4 __attribute__((ext_vector_type(4)));

__device__ __forceinline__ unsigned short f2b(float f) {
    unsigned int u = __float_as_uint(f);
    unsigned int r = u + 0x7FFFu + ((u >> 16) & 1u);   // RNE
    return (unsigned short)(r >> 16);
}
// f32 -> fp8 e4m3 (OCP), RNE via HW cvt
__device__ __forceinline__ unsigned char f2f8(float f) {
    return (unsigned char)(__builtin_amdgcn_cvt_pk_fp8_f32(f, f, 0, false) & 0xFF);
}
template <bool HI>
__device__ __forceinline__ f32x2 f8up2(unsigned int u) {
    return __builtin_amdgcn_cvt_pk_f32_fp8((int)u, HI);
}
__device__ __forceinline__ f32x2 up2(unsigned int u) {
    f32x2 r;
    r.x = __uint_as_float(u << 16);
    r.y = __uint_as_float(u & 0xFFFF0000u);
    return r;
}
__device__ __forceinline__ f32x2 lrelu2(f32x2 s) {
    return __builtin_elementwise_max(s, s * NEG);
}
__device__ __forceinline__ float lrelu(float s) { return fmaxf(s, NEG * s); }

__device__ __forceinline__ void unpack8(uint4 u, float* v) {
    v[0] = __uint_as_float(u.x << 16); v[1] = __uint_as_float(u.x & 0xFFFF0000u);
    v[2] = __uint_as_float(u.y << 16); v[3] = __uint_as_float(u.y & 0xFFFF0000u);
    v[4] = __uint_as_float(u.z << 16); v[5] = __uint_as_float(u.z & 0xFFFF0000u);
    v[6] = __uint_as_float(u.w << 16); v[7] = __uint_as_float(u.w & 0xFFFF0000u);
}
__device__ __forceinline__ void unpack8_f8(uint2 u, float* v) {
    f32x2 a = f8up2<false>(u.x), b = f8up2<true>(u.x);
    f32x2 c = f8up2<false>(u.y), d = f8up2<true>(u.y);
    v[0] = a.x; v[1] = a.y; v[2] = b.x; v[3] = b.y;
    v[4] = c.x; v[5] = c.y; v[6] = d.x; v[7] = d.y;
}

// ---------------- zero: count[] + done flag (unblocks rank ASAP) ------------

__global__ __launch_bounds__(256) void zero_kernel(int* __restrict__ count) {
    int q = blockIdx.x * 256 + threadIdx.x;       // 5120 int4 = 20480 ints
    int4 z; z.x = z.y = z.z = z.w = 0;
    ((int4*)count)[q] = z;
}

// 256-thread two-pass scan of count[0..N_NODES) -> exclusive offsets
__device__ __forceinline__ void scan256(const int* __restrict__ count,
                                        int* __restrict__ offsets,
                                        int* wbuf) {   // >= 8 ints LDS
    const int PER = 79;            // 256*79 = 20224 >= 20000
    int t = threadIdx.x;
    int base = t * PER;
    int sum = 0;
#pragma unroll 8
    for (int i = 0; i < PER; i++) {
        int idx = base + i;
        if (idx < N_NODES) sum += count[idx];
    }
    int lane = t & 63, wave = t >> 6;
    int s = sum;
#pragma unroll
    for (int off = 1; off < 64; off <<= 1) {
        int x = __shfl_up(s, off);
        if (lane >= off) s += x;
    }
    int* wsum = wbuf;
    int* wpre = wbuf + 4;
    if (lane == 63) wsum[wave] = s;
    __syncthreads();
    if (t == 0) {
        int acc = 0;
        for (int w = 0; w < 4; w++) { wpre[w] = acc; acc += wsum[w]; }
    }
    __syncthreads();
    int excl = wpre[wave] + (s - sum);
    if (t == 255) offsets[N_NODES] = excl + sum;   // grand total == ET
    int run = excl;
#pragma unroll 8
    for (int i = 0; i < PER; i++) {
        int idx = base + i;
        if (idx < N_NODES) { offsets[idx] = run; run += count[idx]; }
    }
}

// ------- fused front: rank (critical path) + W^T + xconv; last rank block
//         runs the CSR scan (saves a dispatch + 1-block-kernel latency) ------

__global__ __launch_bounds__(256) void front_kernel(
        const float* __restrict__ gnn_x,
        const float* __restrict__ Wl1, const float* __restrict__ Wr1,
        const float* __restrict__ Wl2, const float* __restrict__ Wr2,
        const int* __restrict__ edge_dst,
        unsigned short* __restrict__ xb,
        unsigned short* __restrict__ wt1l, unsigned short* __restrict__ wt1r,
        unsigned short* __restrict__ wt2l, unsigned short* __restrict__ wt2r,
        int* __restrict__ count, int* __restrict__ done,
        int* __restrict__ rank, int* __restrict__ offsets) {
    __shared__ __align__(16) char smem[8448];     // Wt tile / scan buf
    int bid = blockIdx.x;
    int tid = threadIdx.x;
    if (bid < RANK_BLOCKS) {
        // per-edge slot within dst segment (arbitrary intra-segment order;
        // downstream fp32 segment sums are order-insensitive)
        int e = bid * 256 + tid;
        if (e < ET) {
            int dst = (e < E_EDGES) ? edge_dst[e] : (e - E_EDGES);
            rank[e] = atomicAdd(&count[dst], 1);
        }
        // last-done rank block performs the scan (standard threadfence+counter)
        __shared__ int islast;
        if (tid == 0) {
            __threadfence();
            int old = atomicAdd(done, 1);
            islast = (old == RANK_BLOCKS - 1) ? 1 : 0;
        }
        __syncthreads();
        if (islast) {
            __threadfence();
            scan256(count, offsets, (int*)smem);
        }
    } else if (bid < RANK_BLOCKS + WT_BLOCKS) {
        // W [K x N] -> Wt [N x K] via 64x64 LDS tile; coalesced both sides
        unsigned short* tile = (unsigned short*)smem;    // 64 x 65 bf16
        int t = bid - RANK_BLOCKS;                       // 0..31
        int m = t >> 3;                                  // matrix 0..3
        int tt = t & 7;                                  // tile in matrix
        const float* W;
        unsigned short* Wt;
        int K, N;
        if (m == 0)      { W = Wl1; Wt = wt1l; K = IN_CH; N = D1; }
        else if (m == 1) { W = Wr1; Wt = wt1r; K = IN_CH; N = D1; }
        else if (m == 2) { W = Wl2; Wt = wt2l; K = D1; N = D2; }
        else             { W = Wr2; Wt = wt2r; K = D1; N = D2; }
        int ntn = N >> 6;                                // n-tiles per matrix
        int k0 = (tt / ntn) << 6;
        int n0 = (tt % ntn) << 6;
        int c = tid & 63;
        int rr = tid >> 6;                               // 0..3
#pragma unroll
        for (int ch = 0; ch < 16; ch++) {
            int row = rr * 16 + ch;
            tile[row * 65 + c] = f2b(W[(size_t)(k0 + row) * N + n0 + c]);
        }
        __syncthreads();
#pragma unroll
        for (int ch = 0; ch < 16; ch++) {
            int n = rr * 16 + ch;
            Wt[(size_t)(n0 + n) * K + k0 + c] = tile[c * 65 + n];
        }
    } else {
        // x -> bf16 with zero row padding; ILP-4, NT load
        int t = (bid - RANK_BLOCKS - WT_BLOCKS) * 256 + tid;
        const int NQ = M_PAD * IN_CH / 4;  // total float4 groups
        int q0 = t * 4;
#pragma unroll
        for (int j = 0; j < 4; j++) {
            int qi = q0 + j;
            if (qi >= NQ) break;
            int e0 = qi * 4;
            int row = e0 >> 8;             // / IN_CH
            u16x4 o;
            if (row < N_NODES) {
                f32x4 v = __builtin_nontemporal_load((const f32x4*)(gnn_x + e0));
                o.x = f2b(v.x); o.y = f2b(v.y); o.z = f2b(v.z); o.w = f2b(v.w);
            } else {
                o.x = o.y = o.z = o.w = 0;
            }
            *(u16x4*)(xb + e0) = o;
        }
    }
}

// -------- dual GEMM tile (device body, 16 cols/wave; Yl fp8, Yr bf16) -------

template <int K>
__device__ __forceinline__ void dual_gemm_tile(
        const unsigned short* __restrict__ A,
        const unsigned short* __restrict__ Wtl,
        const unsigned short* __restrict__ Wtr,
        const float* __restrict__ bl, const float* __restrict__ br,
        unsigned char* __restrict__ Yl, unsigned short* __restrict__ Yr,
        int M, int NOUT, int bx, int by) {
    const int NK = K / 32;
    int wave = threadIdx.x >> 6;
    int lane = threadIdx.x & 63;
    int row0 = bx * 64;
    int col0 = (by * 4 + wave) * 16;
    int rsub = lane & 15;
    int koff = (lane >> 4) * 8;

    const unsigned short* ap  = A   + (size_t)(row0 + rsub) * K + koff;
    const unsigned short* bpl = Wtl + (size_t)(col0 + rsub) * K + koff;
    const unsigned short* bpr = Wtr + (size_t)(col0 + rsub) * K + koff;

    bf16x8 bfl[NK], bfr[NK];
#pragma unroll
    for (int kb = 0; kb < NK; kb++) {
        bfl[kb] = *(const bf16x8*)(bpl + kb * 32);
        bfr[kb] = *(const bf16x8*)(bpr + kb * 32);
    }

    f32x4 l0 = {0.f, 0.f, 0.f, 0.f};
    f32x4 l1 = l0, l2 = l0, l3 = l0, r0 = l0, r1 = l0, r2 = l0, r3 = l0;

#pragma unroll
    for (int kb = 0; kb < NK; kb++) {
        int off = kb * 32;
        bf16x8 a0 = *(const bf16x8*)(ap + off);
        bf16x8 a1 = *(const bf16x8*)(ap + 16 * K + off);
        bf16x8 a2 = *(const bf16x8*)(ap + 32 * K + off);
        bf16x8 a3 = *(const bf16x8*)(ap + 48 * K + off);
        l0 = __builtin_amdgcn_mfma_f32_16x16x32_bf16(a0, bfl[kb], l0, 0, 0, 0);
        r0 = __builtin_amdgcn_mfma_f32_16x16x32_bf16(a0, bfr[kb], r0, 0, 0, 0);
        l1 = __builtin_amdgcn_mfma_f32_16x16x32_bf16(a1, bfl[kb], l1, 0, 0, 0);
        r1 = __builtin_amdgcn_mfma_f32_16x16x32_bf16(a1, bfr[kb], r1, 0, 0, 0);
        l2 = __builtin_amdgcn_mfma_f32_16x16x32_bf16(a2, bfl[kb], l2, 0, 0, 0);
        r2 = __builtin_amdgcn_mfma_f32_16x16x32_bf16(a2, bfr[kb], r2, 0, 0, 0);
        l3 = __builtin_amdgcn_mfma_f32_16x16x32_bf16(a3, bfl[kb], l3, 0, 0, 0);
        r3 = __builtin_amdgcn_mfma_f32_16x16x32_bf16(a3, bfr[kb], r3, 0, 0, 0);
    }

    int colg = col0 + rsub;
    float bvl = bl[colg];
    float bvr = br[colg];
    int rbase = row0 + (lane >> 4) * 4;
#pragma unroll
    for (int t = 0; t < 4; t++) {
        f32x4 al = (t == 0) ? l0 : (t == 1) ? l1 : (t == 2) ? l2 : l3;
        f32x4 ar = (t == 0) ? r0 : (t == 1) ? r1 : (t == 2) ? r2 : r3;
#pragma unroll
        for (int r = 0; r < 4; r++) {
            int row = rbase + t * 16 + r;
            if (row < M) {
                Yl[(size_t)row * NOUT + colg] = f2f8(al[r] + bvl);
                Yr[(size_t)row * NOUT + colg] = f2b(ar[r] + bvr);
            }
        }
    }
}

// ---------------- merged: gemm1 (layer-1 dual GEMM) + edge scatter ----------

__global__ __launch_bounds__(256) void gemm1_scatter_kernel(
        const unsigned short* __restrict__ A,
        const unsigned short* __restrict__ Wtl,
        const unsigned short* __restrict__ Wtr,
        const float* __restrict__ bl, const float* __restrict__ br,
        unsigned char* __restrict__ Yl, unsigned short* __restrict__ Yr,
        const int* __restrict__ edge_src, const int* __restrict__ edge_dst,
        const int* __restrict__ rank, const int* __restrict__ offsets,
        int* __restrict__ sorted_src) {
    int bid = blockIdx.x;
    if (bid < G1_BLOCKS) {
        dual_gemm_tile<IN_CH>(A, Wtl, Wtr, bl, br, Yl, Yr,
                              N_NODES, D1, bid % G1X, bid / G1X);
    } else {
        int e = (bid - G1_BLOCKS) * 256 + threadIdx.x;
        if (e >= ET) return;
        int dst = (e < E_EDGES) ? edge_dst[e] : (e - E_EDGES);
        int src = (e < E_EDGES) ? edge_src[e] : (e - E_EDGES);
        sorted_src[offsets[dst] + rank[e]] = src;
    }
}

// -------- gemm2: 32 cols/wave (16 MFMA per 4 A-loads); Yl fp8, Yr bf16 ------

template <int K>
__global__ __launch_bounds__(256) void dual_gemm_w32_kernel(
        const unsigned short* __restrict__ A,
        const unsigned short* __restrict__ Wtl,
        const unsigned short* __restrict__ Wtr,
        const float* __restrict__ bl, const float* __restrict__ br,
        unsigned char* __restrict__ Yl, unsigned short* __restrict__ Yr,
        int M, int NOUT) {
    const int NK = K / 32;
    int wave = threadIdx.x >> 6;
    int lane = threadIdx.x & 63;
    int row0 = blockIdx.x * 64;
    int col0 = blockIdx.y * 128 + wave * 32;
    int rsub = lane & 15;
    int koff = (lane >> 4) * 8;

    const unsigned short* ap = A + (size_t)(row0 + rsub) * K + koff;

    bf16x8 bfl[2][NK], bfr[2][NK];
#pragma unroll
    for (int c = 0; c < 2; c++) {
        const unsigned short* bpl = Wtl + (size_t)(col0 + c * 16 + rsub) * K + koff;
        const unsigned short* bpr = Wtr + (size_t)(col0 + c * 16 + rsub) * K + koff;
#pragma unroll
        for (int kb = 0; kb < NK; kb++) {
            bfl[c][kb] = *(const bf16x8*)(bpl + kb * 32);
            bfr[c][kb] = *(const bf16x8*)(bpr + kb * 32);
        }
    }

    f32x4 accl[2][4], accr[2][4];
#pragma unroll
    for (int c = 0; c < 2; c++)
#pragma unroll
        for (int t = 0; t < 4; t++) {
            accl[c][t] = (f32x4){0.f, 0.f, 0.f, 0.f};
            accr[c][t] = (f32x4){0.f, 0.f, 0.f, 0.f};
        }

#pragma unroll
    for (int kb = 0; kb < NK; kb++) {
        int off = kb * 32;
        bf16x8 a[4];
        a[0] = *(const bf16x8*)(ap + off);
        a[1] = *(const bf16x8*)(ap + 16 * K + off);
        a[2] = *(const bf16x8*)(ap + 32 * K + off);
        a[3] = *(const bf16x8*)(ap + 48 * K + off);
#pragma unroll
        for (int t = 0; t < 4; t++) {
#pragma unroll
            for (int c = 0; c < 2; c++) {
                accl[c][t] = __builtin_amdgcn_mfma_f32_16x16x32_bf16(
                    a[t], bfl[c][kb], accl[c][t], 0, 0, 0);
                accr[c][t] = __builtin_amdgcn_mfma_f32_16x16x32_bf16(
                    a[t], bfr[c][kb], accr[c][t], 0, 0, 0);
            }
        }
    }

    int rbase = row0 + (lane >> 4) * 4;
#pragma unroll
    for (int c = 0; c < 2; c++) {
        int colg = col0 + c * 16 + rsub;
        float bvl = bl[colg];
        float bvr = br[colg];
#pragma unroll
        for (int t = 0; t < 4; t++) {
#pragma unroll
            for (int r = 0; r < 4; r++) {
                int row = rbase + t * 16 + r;
                if (row < M) {
                    Yl[(size_t)row * NOUT + colg] = f2f8(accl[c][t][r] + bvl);
                    Yr[(size_t)row * NOUT + colg] = f2b(accr[c][t][r] + bvr);
                }
            }
        }
    }
}

// -------- layer 1 aggregation (quarter-wave per edge, prefetch-2, fp8) ------

__global__ __launch_bounds__(256) void aggregate1_kernel(
        const unsigned char* __restrict__ xl1, const unsigned short* __restrict__ xr1,
        const float* __restrict__ att1, const float* __restrict__ bias1,
        const int* __restrict__ offsets, const int* __restrict__ sorted_src,
        unsigned short* __restrict__ x1) {
    int wave = threadIdx.x >> 6;
    int lane = threadIdx.x & 63;
    int q = lane >> 4;                 // quarter 0..3
    int ql = lane & 15;
    int dst = blockIdx.x * 4 + wave;
    if (dst >= M_PAD) return;
    int c0 = ql * 8;                   // channel index (8 ch/lane)
    if (dst >= N_NODES) {              // zero pad rows for the next GEMM
        if (q == 0) {
            uint4 z; z.x = z.y = z.z = z.w = 0;
            *(uint4*)(x1 + (size_t)dst * D1 + c0) = z;
        }
        return;
    }

    uint4 xu = *(const uint4*)(xr1 + (size_t)dst * D1 + c0);
    f32x2 xr[4] = {up2(xu.x), up2(xu.y), up2(xu.z), up2(xu.w)};
    float4 aa0 = *(const float4*)(att1 + c0);
    float4 aa1 = *(const float4*)(att1 + c0 + 4);
    f32x2 att[4];
    att[0].x = aa0.x * LOG2E; att[0].y = aa0.y * LOG2E;
    att[1].x = aa0.z * LOG2E; att[1].y = aa0.w * LOG2E;
    att[2].x = aa1.x * LOG2E; att[2].y = aa1.y * LOG2E;
    att[3].x = aa1.z * LOG2E; att[3].y = aa1.w * LOG2E;

    int beg = offsets[dst], end = offsets[dst + 1];
    const unsigned char* base = xl1 + c0;   // fp8: 1 byte/ch, row stride D1 B

    float l = 0.f;
    f32x2 acc[4] = {{0.f,0.f},{0.f,0.f},{0.f,0.f},{0.f,0.f}};

    int i = beg;
    int s0 = sorted_src[min(i + q, end - 1)];
    uint2 g0 = *(const uint2*)(base + (size_t)s0 * D1);
    bool more1 = (i + 4) < end;
    uint2 g1;
    if (more1) {
        int s1 = sorted_src[min(i + 4 + q, end - 1)];
        g1 = *(const uint2*)(base + (size_t)s1 * D1);
    }
    while (true) {
        bool more2 = (i + 8) < end;
        uint2 g2;
        if (more2) {
            int s2 = sorted_src[min(i + 8 + q, end - 1)];
            g2 = *(const uint2*)(base + (size_t)s2 * D1);
        }
        bool act = (i + q) < end;
        f32x2 v0 = f8up2<false>(g0.x), v1 = f8up2<true>(g0.x);
        f32x2 v2 = f8up2<false>(g0.y), v3 = f8up2<true>(g0.y);
        f32x2 p2 = att[0] * lrelu2(v0 + xr[0]);
        p2 += att[1] * lrelu2(v1 + xr[1]);
        p2 += att[2] * lrelu2(v2 + xr[2]);
        p2 += att[3] * lrelu2(v3 + xr[3]);
        float p = p2.x + p2.y;
        p += __shfl_xor(p, 1);          // head reduce (2 lanes/head)
        float w = act ? EXP2F(p) : 0.f;
        l += w;
        acc[0] += w * v0; acc[1] += w * v1; acc[2] += w * v2; acc[3] += w * v3;
        if (!more1) break;
        i += 4;
        g0 = g1; g1 = g2; more1 = more2;
    }
    // merge quarters
    l += __shfl_xor(l, 16);
    l += __shfl_xor(l, 32);
#pragma unroll
    for (int j = 0; j < 4; j++) {
        f32x2 t;
        t.x = __shfl_xor(acc[j].x, 16); t.y = __shfl_xor(acc[j].y, 16);
        acc[j] += t;
        t.x = __shfl_xor(acc[j].x, 32); t.y = __shfl_xor(acc[j].y, 32);
        acc[j] += t;
    }
    if (q == 0) {
        float inv = 1.f / l;
        float4 bb0 = *(const float4*)(bias1 + c0);
        float4 bb1 = *(const float4*)(bias1 + c0 + 4);
        unsigned short o[8];
        o[0] = f2b(fmaxf(acc[0].x * inv + bb0.x, 0.f));
        o[1] = f2b(fmaxf(acc[0].y * inv + bb0.y, 0.f));
        o[2] = f2b(fmaxf(acc[1].x * inv + bb0.z, 0.f));
        o[3] = f2b(fmaxf(acc[1].y * inv + bb0.w, 0.f));
        o[4] = f2b(fmaxf(acc[2].x * inv + bb1.x, 0.f));
        o[5] = f2b(fmaxf(acc[2].y * inv + bb1.y, 0.f));
        o[6] = f2b(fmaxf(acc[3].x * inv + bb1.z, 0.f));
        o[7] = f2b(fmaxf(acc[3].y * inv + bb1.w, 0.f));
        uint4 ov;
        ov.x = (unsigned int)o[0] | ((unsigned int)o[1] << 16);
        ov.y = (unsigned int)o[2] | ((unsigned int)o[3] << 16);
        ov.z = (unsigned int)o[4] | ((unsigned int)o[5] << 16);
        ov.w = (unsigned int)o[6] | ((unsigned int)o[7] << 16);
        *(uint4*)(x1 + (size_t)dst * D1 + c0) = ov;
    }
}

// ------- fused layer-2 aggregation + classifier: one block per pair ---------

__global__ __launch_bounds__(256) void agg2_classifier_kernel(
        const unsigned char* __restrict__ xl2, const unsigned short* __restrict__ xr2,
        const float* __restrict__ att2, const float* __restrict__ bias2,
        const int* __restrict__ offsets, const int* __restrict__ sorted_src,
        const float* __restrict__ vanilla_x,
        const int* __restrict__ a1_raw, const int* __restrict__ a2_raw,
        const float* __restrict__ Wc, const float* __restrict__ bc,
        float* __restrict__ out) {
    __shared__ float x2row[2][D2];     // 2 KB
    __shared__ float mrg[2][32][9];    // 2.25 KB
    __shared__ float part[4];
    __shared__ int stride_s;
    int t = threadIdx.x;
    if (t < 64) {
        // int64 indices have zero odd words (values << 2^31); detect in parallel
        bool z = (t < 31) ? (a1_raw[1 + 2 * t] == 0) : true;
        unsigned long long m = __ballot(z);
        if (t == 0) stride_s = (m == ~0ull) ? 2 : 1;
    }
    __syncthreads();
    int stride = stride_s;
    int b = blockIdx.x;
    int a1 = a1_raw[(long)b * stride];
    int a2 = a2_raw[(long)b * stride];

    int wave = t >> 6;                 // 0..3
    int d = wave >> 1;                 // dst slot 0/1
    int ww = wave & 1;                 // wave within pair
    int lane = t & 63;
    int half = lane >> 5;
    int hl = lane & 31;
    int c0 = hl * 8;
    int dst = d ? a2 : a1;

    float xr[8], att[8];
    unpack8(*(const uint4*)(xr2 + (size_t)dst * D2 + c0), xr);
#pragma unroll
    for (int j = 0; j < 8; j++) att[j] = att2[c0 + j] * LOG2E;
    int beg = offsets[dst], end = offsets[dst + 1];
    const unsigned char* base = xl2 + c0;

    float l = 0.f;
    float acc[8];
#pragma unroll
    for (int j = 0; j < 8; j++) acc[j] = 0.f;

    int sub = 2 * ww + half;           // edge slot 0..3
    int i = beg;
    int s0 = sorted_src[min(i + sub, end - 1)];
    uint2 g0 = *(const uint2*)(base + (size_t)s0 * D2);
    bool more1 = (i + 4) < end;
    uint2 g1;
    if (more1) {
        int s1 = sorted_src[min(i + 4 + sub, end - 1)];
        g1 = *(const uint2*)(base + (size_t)s1 * D2);
    }
    while (true) {
        bool more2 = (i + 8) < end;
        uint2 g2;
        if (more2) {
            int s2 = sorted_src[min(i + 8 + sub, end - 1)];
            g2 = *(const uint2*)(base + (size_t)s2 * D2);
        }
        bool act = (i + sub) < end;
        float v[8];
        unpack8_f8(g0, v);
        float p = 0.f;
#pragma unroll
        for (int j = 0; j < 8; j++) p = fmaf(att[j], lrelu(v[j] + xr[j]), p);
        p += __shfl_xor(p, 1);
        p += __shfl_xor(p, 2);
        p += __shfl_xor(p, 4);
        p += __shfl_xor(p, 8);
        p += __shfl_xor(p, 16);
        float w = act ? EXP2F(p) : 0.f;
        l += w;
#pragma unroll
        for (int j = 0; j < 8; j++) acc[j] += w * v[j];
        if (!more1) break;
        i += 4;
        g0 = g1; g1 = g2; more1 = more2;
    }
    // merge halves within wave
    l += __shfl_xor(l, 32);
#pragma unroll
    for (int j = 0; j < 8; j++) acc[j] += __shfl_xor(acc[j], 32);
    // merge across the wave pair via LDS
    if (ww == 1 && half == 0) {
        mrg[d][hl][0] = l;
#pragma unroll
        for (int j = 0; j < 8; j++) mrg[d][hl][1 + j] = acc[j];
    }
    __syncthreads();
    if (ww == 0 && half == 0) {
        l += mrg[d][hl][0];
#pragma unroll
        for (int j = 0; j < 8; j++) acc[j] += mrg[d][hl][1 + j];
        float inv = 1.f / l;
#pragma unroll
        for (int j = 0; j < 8; j++)
            x2row[d][c0 + j] = acc[j] * inv + bias2[c0 + j];
    }
    __syncthreads();

    // classifier dot: thread t owns channel t of each of the 4 segments
    float s = vanilla_x[(size_t)a1 * IN_CH + t] * Wc[t]
            + vanilla_x[(size_t)a2 * IN_CH + t] * Wc[IN_CH + t]
            + x2row[0][t] * Wc[2 * IN_CH + t]
            + x2row[1][t] * Wc[3 * IN_CH + t];
    s += __shfl_xor(s, 1);
    s += __shfl_xor(s, 2);
    s += __shfl_xor(s, 4);
    s += __shfl_xor(s, 8);
    s += __shfl_xor(s, 16);
    s += __shfl_xor(s, 32);
    if (lane == 0) part[wave] = s;
    __syncthreads();
    if (t == 0) out[b] = part[0] + part[1] + part[2] + part[3] + bc[0];
}

// ---------------- launch ----------------

extern "C" void kernel_launch(void* const* d_in, const int* in_sizes, int n_in,
                              void* d_out, int out_size, void* d_ws, size_t ws_size,
                              hipStream_t stream) {
    const float* gnn_x     = (const float*)d_in[0];
    const float* vanilla_x = (const float*)d_in[1];
    const int*   edge_src  = (const int*)d_in[2];
    const int*   edge_dst  = (const int*)d_in[3];
    const int*   a1_idx    = (const int*)d_in[4];
    const int*   a2_idx    = (const int*)d_in[5];
    const float* Wl1   = (const float*)d_in[6];
    const float* bl1   = (const float*)d_in[7];
    const float* Wr1   = (const float*)d_in[8];
    const float* br1   = (const float*)d_in[9];
    const float* att1  = (const float*)d_in[10];
    const float* bias1 = (const float*)d_in[11];
    const float* Wl2   = (const float*)d_in[12];
    const float* bl2   = (const float*)d_in[13];
    const float* Wr2   = (const float*)d_in[14];
    const float* br2   = (const float*)d_in[15];
    const float* att2  = (const float*)d_in[16];
    const float* bias2 = (const float*)d_in[17];
    const float* Wc    = (const float*)d_in[18];
    const float* bc    = (const float*)d_in[19];
    float* out = (float*)d_out;

    // workspace layout (~45 MB)
    char* p = (char*)d_ws;
    unsigned short* xb   = (unsigned short*)p; p += (size_t)M_PAD * IN_CH * 2;
    unsigned short* x1b  = (unsigned short*)p; p += (size_t)M_PAD * D1 * 2;
    unsigned char*  xl1b = (unsigned char*)p;  p += (size_t)N_NODES * D1;      // fp8
    unsigned short* xr1b = (unsigned short*)p; p += (size_t)N_NODES * D1 * 2;
    unsigned char*  xl2b = (unsigned char*)p;  p += (size_t)N_NODES * D2;      // fp8
    unsigned short* xr2b = (unsigned short*)p; p += (size_t)N_NODES * D2 * 2;
    unsigned short* wt1l = (unsigned short*)p; p += (size_t)D1 * IN_CH * 2;
    unsigned short* wt1r = (unsigned short*)p; p += (size_t)D1 * IN_CH * 2;
    unsigned short* wt2l = (unsigned short*)p; p += (size_t)D2 * D1 * 2;
    unsigned short* wt2r = (unsigned short*)p; p += (size_t)D2 * D1 * 2;
    int* count      = (int*)p; p += (size_t)20480 * 4;   // count[20000] + done + pad
    int* offsets    = (int*)p; p += (size_t)(N_NODES + 4) * 4;
    int* rank       = (int*)p; p += (size_t)ET * 4;
    int* sorted_src = (int*)p; p += (size_t)ET * 4;
    int* done = count + 20032;

    // A: zero count+done (tiny; unblocks rank without waiting on xconv)
    zero_kernel<<<ZERO_BLOCKS, 256, 0, stream>>>(count);

    // B: rank (critical path, blocks first) || W^T || xconv; last rank block
    //    runs the CSR scan in its tail
    front_kernel<<<FRONT_BLOCKS, 256, 0, stream>>>(
        gnn_x, Wl1, Wr1, Wl2, Wr2, edge_dst,
        xb, wt1l, wt1r, wt2l, wt2r, count, done, rank, offsets);

    // C: layer-1 dual GEMM + edge scatter (independent; one dispatch)
    gemm1_scatter_kernel<<<G1_BLOCKS + SCAT_BLOCKS, 256, 0, stream>>>(
        xb, wt1l, wt1r, bl1, br1, xl1b, xr1b,
        edge_src, edge_dst, rank, offsets, sorted_src);

    // D: layer-1 aggregation
    aggregate1_kernel<<<M_PAD / 4, 256, 0, stream>>>(
        xl1b, xr1b, att1, bias1, offsets, sorted_src, x1b);

    // E: layer-2 dual GEMM (32 cols/wave)
    dim3 g2(M_PAD / 64, D2 / 128);   // (313, 2)
    dual_gemm_w32_kernel<D1><<<g2, 256, 0, stream>>>(
        x1b, wt2l, wt2r, bl2, br2, xl2b, xr2b, N_NODES, D2);

    // F: fused layer-2 aggregation + classifier (one block per pair)
    agg2_classifier_kernel<<<BPAIRS, 256, 0, stream>>>(
        xl2b, xr2b, att2, bias2, offsets, sorted_src,
        vanilla_x, a1_idx, a2_idx, Wc, bc, out);
}

// Round 5
// 314.210 us; speedup vs baseline: 2.3524x; 1.1212x over previous
//
#include <hip/hip_runtime.h>
#include <math.h>

#define N_NODES 20000
#define M_PAD   20032            // 64-row padded for MFMA row tiles
#define E_EDGES 640000
#define ET (E_EDGES + N_NODES)   // edges + self loops
#define IN_CH 256
#define D1 128                   // H1*C1 = 8*16
#define D2 256                   // H2*C2 = 1*256
#define BPAIRS 4096
#define NEG 0.2f
#define LOG2E 1.4426950408889634f

#define ZC_BLOCKS    40                            // zero 10240 int4 = 40960 ints
#define WT_BLOCKS    32                            // 4 matrices x 8 64x64 tiles
#define XCONV_BLOCKS (M_PAD * IN_CH / 4 / 4 / 256) // 1252 (ILP-4)
#define PREP_BLOCKS  (ZC_BLOCKS + WT_BLOCKS + XCONV_BLOCKS)

#define COUNT_BLOCKS ((ET + 255) / 256)            // 2579
#define SCAT_BLOCKS  ((ET + 255) / 256)            // 2579
#define G1X (M_PAD / 64)             // 313
#define G1_BLOCKS (G1X * (D1 / 64))  // 626
#define K2_GEMM0 (1 + COUNT_BLOCKS)             // 2580
#define K2_SCAT0 (K2_GEMM0 + G1_BLOCKS)         // 3206
#define K2_BLOCKS (K2_SCAT0 + SCAT_BLOCKS)      // 5785

#if __has_builtin(__builtin_amdgcn_exp2f)
#define EXP2F(x) __builtin_amdgcn_exp2f(x)
#else
#define EXP2F(x) exp2f(x)
#endif

typedef __bf16 bf16x8 __attribute__((ext_vector_type(8)));
typedef float  f32x4  __attribute__((ext_vector_type(4)));
typedef float  f32x2  __attribute__((ext_vector_type(2)));
typedef unsigned short u16x4 __attribute__((ext_vector_type(4)));

__device__ __forceinline__ unsigned short f2b(float f) {
    unsigned int u = __float_as_uint(f);
    unsigned int r = u + 0x7FFFu + ((u >> 16) & 1u);   // RNE
    return (unsigned short)(r >> 16);
}
// f32 -> fp8 e4m3 (OCP), RNE via HW cvt
__device__ __forceinline__ unsigned char f2f8(float f) {
    return (unsigned char)(__builtin_amdgcn_cvt_pk_fp8_f32(f, f, 0, false) & 0xFF);
}
template <bool HI>
__device__ __forceinline__ f32x2 f8up2(unsigned int u) {
    return __builtin_amdgcn_cvt_pk_f32_fp8((int)u, HI);
}
__device__ __forceinline__ f32x2 up2(unsigned int u) {
    f32x2 r;
    r.x = __uint_as_float(u << 16);
    r.y = __uint_as_float(u & 0xFFFF0000u);
    return r;
}
__device__ __forceinline__ f32x2 lrelu2(f32x2 s) {
    return __builtin_elementwise_max(s, s * NEG);
}
__device__ __forceinline__ float lrelu(float s) { return fmaxf(s, NEG * s); }

__device__ __forceinline__ void unpack8(uint4 u, float* v) {
    v[0] = __uint_as_float(u.x << 16); v[1] = __uint_as_float(u.x & 0xFFFF0000u);
    v[2] = __uint_as_float(u.y << 16); v[3] = __uint_as_float(u.y & 0xFFFF0000u);
    v[4] = __uint_as_float(u.z << 16); v[5] = __uint_as_float(u.z & 0xFFFF0000u);
    v[6] = __uint_as_float(u.w << 16); v[7] = __uint_as_float(u.w & 0xFFFF0000u);
}
__device__ __forceinline__ void unpack8_f8(uint2 u, float* v) {
    f32x2 a = f8up2<false>(u.x), b = f8up2<true>(u.x);
    f32x2 c = f8up2<false>(u.y), d = f8up2<true>(u.y);
    v[0] = a.x; v[1] = a.y; v[2] = b.x; v[3] = b.y;
    v[4] = c.x; v[5] = c.y; v[6] = d.x; v[7] = d.y;
}

__device__ __forceinline__ int aload(const int* p) {
    return __hip_atomic_load(p, __ATOMIC_RELAXED, __HIP_MEMORY_SCOPE_AGENT);
}

// ------- K1 prep: zero(count/cursor/done/flag) + LDS-tiled W^T + xconv ------

__global__ __launch_bounds__(256) void prep_kernel(
        const float* __restrict__ gnn_x,
        const float* __restrict__ Wl1, const float* __restrict__ Wr1,
        const float* __restrict__ Wl2, const float* __restrict__ Wr2,
        unsigned short* __restrict__ xb,
        unsigned short* __restrict__ wt1l, unsigned short* __restrict__ wt1r,
        unsigned short* __restrict__ wt2l, unsigned short* __restrict__ wt2r,
        int* __restrict__ ibuf) {
    __shared__ __align__(16) unsigned short tile[64 * 65];   // 8.3 KB
    int bid = blockIdx.x;
    if (bid < ZC_BLOCKS) {
        // zero count[20000] @0, cursor[20000] @20032, done/flag @40064+
        int q = bid * 256 + threadIdx.x;      // 10240 int4 = 40960 ints exact
        int4 z; z.x = z.y = z.z = z.w = 0;
        ((int4*)ibuf)[q] = z;
    } else if (bid < ZC_BLOCKS + WT_BLOCKS) {
        // W [K x N] -> Wt [N x K] via 64x64 LDS tile; coalesced both sides
        int t = bid - ZC_BLOCKS;                         // 0..31
        int m = t >> 3;                                  // matrix 0..3
        int tt = t & 7;                                  // tile in matrix
        const float* W;
        unsigned short* Wt;
        int K, N;
        if (m == 0)      { W = Wl1; Wt = wt1l; K = IN_CH; N = D1; }
        else if (m == 1) { W = Wr1; Wt = wt1r; K = IN_CH; N = D1; }
        else if (m == 2) { W = Wl2; Wt = wt2l; K = D1; N = D2; }
        else             { W = Wr2; Wt = wt2r; K = D1; N = D2; }
        int ntn = N >> 6;                                // n-tiles per matrix
        int k0 = (tt / ntn) << 6;
        int n0 = (tt % ntn) << 6;
        int c = threadIdx.x & 63;
        int rr = threadIdx.x >> 6;                       // 0..3
#pragma unroll
        for (int ch = 0; ch < 16; ch++) {
            int row = rr * 16 + ch;
            tile[row * 65 + c] = f2b(W[(size_t)(k0 + row) * N + n0 + c]);
        }
        __syncthreads();
#pragma unroll
        for (int ch = 0; ch < 16; ch++) {
            int n = rr * 16 + ch;
            Wt[(size_t)(n0 + n) * K + k0 + c] = tile[c * 65 + n];
        }
    } else {
        // x -> bf16 with zero row padding; ILP-4, NT load
        int tid = (bid - ZC_BLOCKS - WT_BLOCKS) * 256 + threadIdx.x;
        const int NQ = M_PAD * IN_CH / 4;  // total float4 groups
        int q0 = tid * 4;
#pragma unroll
        for (int j = 0; j < 4; j++) {
            int qi = q0 + j;
            if (qi >= NQ) break;
            int e0 = qi * 4;
            int row = e0 >> 8;             // / IN_CH
            u16x4 o;
            if (row < N_NODES) {
                f32x4 v = __builtin_nontemporal_load((const f32x4*)(gnn_x + e0));
                o.x = f2b(v.x); o.y = f2b(v.y); o.z = f2b(v.z); o.w = f2b(v.w);
            } else {
                o.x = o.y = o.z = o.w = 0;
            }
            *(u16x4*)(xb + e0) = o;
        }
    }
}

// 256-thread two-pass scan of count[0..N_NODES) -> exclusive offsets
__device__ __forceinline__ void scan256(const int* __restrict__ count,
                                        int* __restrict__ offsets,
                                        int* wbuf) {   // >= 8 ints LDS
    const int PER = 79;            // 256*79 = 20224 >= 20000
    int t = threadIdx.x;
    int base = t * PER;
    int sum = 0;
#pragma unroll 8
    for (int i = 0; i < PER; i++) {
        int idx = base + i;
        if (idx < N_NODES) sum += count[idx];
    }
    int lane = t & 63, wave = t >> 6;
    int s = sum;
#pragma unroll
    for (int off = 1; off < 64; off <<= 1) {
        int x = __shfl_up(s, off);
        if (lane >= off) s += x;
    }
    int* wsum = wbuf;
    int* wpre = wbuf + 4;
    if (lane == 63) wsum[wave] = s;
    __syncthreads();
    if (t == 0) {
        int acc = 0;
        for (int w = 0; w < 4; w++) { wpre[w] = acc; acc += wsum[w]; }
    }
    __syncthreads();
    int excl = wpre[wave] + (s - sum);
    if (t == 255) offsets[N_NODES] = excl + sum;   // grand total == ET
    int run = excl;
#pragma unroll 8
    for (int i = 0; i < PER; i++) {
        int idx = base + i;
        if (idx < N_NODES) { offsets[idx] = run; run += count[idx]; }
    }
}

// dual GEMM 64x64 tile; B loaded inside k-loop (moderate VGPR; K2 filler)
template <int K>
__device__ __forceinline__ void dual_gemm_tile(
        const unsigned short* __restrict__ A,
        const unsigned short* __restrict__ Wtl,
        const unsigned short* __restrict__ Wtr,
        const float* __restrict__ bl, const float* __restrict__ br,
        unsigned char* __restrict__ Yl, unsigned short* __restrict__ Yr,
        int M, int NOUT, int bx, int by) {
    const int NK = K / 32;
    int wave = threadIdx.x >> 6;
    int lane = threadIdx.x & 63;
    int row0 = bx * 64;
    int col0 = (by * 4 + wave) * 16;
    int rsub = lane & 15;
    int koff = (lane >> 4) * 8;

    const unsigned short* ap  = A   + (size_t)(row0 + rsub) * K + koff;
    const unsigned short* bpl = Wtl + (size_t)(col0 + rsub) * K + koff;
    const unsigned short* bpr = Wtr + (size_t)(col0 + rsub) * K + koff;

    f32x4 l0 = {0.f, 0.f, 0.f, 0.f};
    f32x4 l1 = l0, l2 = l0, l3 = l0, r0 = l0, r1 = l0, r2 = l0, r3 = l0;

#pragma unroll
    for (int kb = 0; kb < NK; kb++) {
        int off = kb * 32;
        bf16x8 bfl = *(const bf16x8*)(bpl + off);
        bf16x8 bfr = *(const bf16x8*)(bpr + off);
        bf16x8 a0 = *(const bf16x8*)(ap + off);
        bf16x8 a1 = *(const bf16x8*)(ap + 16 * K + off);
        bf16x8 a2 = *(const bf16x8*)(ap + 32 * K + off);
        bf16x8 a3 = *(const bf16x8*)(ap + 48 * K + off);
        l0 = __builtin_amdgcn_mfma_f32_16x16x32_bf16(a0, bfl, l0, 0, 0, 0);
        r0 = __builtin_amdgcn_mfma_f32_16x16x32_bf16(a0, bfr, r0, 0, 0, 0);
        l1 = __builtin_amdgcn_mfma_f32_16x16x32_bf16(a1, bfl, l1, 0, 0, 0);
        r1 = __builtin_amdgcn_mfma_f32_16x16x32_bf16(a1, bfr, r1, 0, 0, 0);
        l2 = __builtin_amdgcn_mfma_f32_16x16x32_bf16(a2, bfl, l2, 0, 0, 0);
        r2 = __builtin_amdgcn_mfma_f32_16x16x32_bf16(a2, bfr, r2, 0, 0, 0);
        l3 = __builtin_amdgcn_mfma_f32_16x16x32_bf16(a3, bfl, l3, 0, 0, 0);
        r3 = __builtin_amdgcn_mfma_f32_16x16x32_bf16(a3, bfr, r3, 0, 0, 0);
    }

    int colg = col0 + rsub;
    float bvl = bl[colg];
    float bvr = br[colg];
    int rbase = row0 + (lane >> 4) * 4;
#pragma unroll
    for (int t = 0; t < 4; t++) {
        f32x4 al = (t == 0) ? l0 : (t == 1) ? l1 : (t == 2) ? l2 : l3;
        f32x4 ar = (t == 0) ? r0 : (t == 1) ? r1 : (t == 2) ? r2 : r3;
#pragma unroll
        for (int r = 0; r < 4; r++) {
            int row = rbase + t * 16 + r;
            if (row < M) {
                Yl[(size_t)row * NOUT + colg] = f2f8(al[r] + bvl);
                Yr[(size_t)row * NOUT + colg] = f2b(ar[r] + bvr);
            }
        }
    }
}

// ------- K2: count + scan + scatter + gemm1, one dispatch, atomic-only
//         cross-block signaling (no per-block fences — round-4 lesson) -------

__global__ __launch_bounds__(256) void sort_gemm1_kernel(
        const int* __restrict__ edge_src, const int* __restrict__ edge_dst,
        int* __restrict__ count, int* __restrict__ cursor,
        int* __restrict__ done, int* __restrict__ flag,
        int* __restrict__ offsets, int* __restrict__ sorted_src,
        const unsigned short* __restrict__ A,
        const unsigned short* __restrict__ Wtl,
        const unsigned short* __restrict__ Wtr,
        const float* __restrict__ bl, const float* __restrict__ br,
        unsigned char* __restrict__ Yl, unsigned short* __restrict__ Yr) {
    __shared__ int wbuf[8];
    int bid = blockIdx.x, tid = threadIdx.x;
    if (bid == 0) {
        // scan block: wait until all count blocks signalled, then CSR scan.
        // count values are device-scope-atomic-written -> coherence point;
        // our plain loads first-touch them fresh (L2 invalidated at launch).
        if (tid == 0) {
            int guard = 0;
            while (aload(done) < COUNT_BLOCKS && guard < (1 << 30)) {
                __builtin_amdgcn_s_sleep(8); guard++;
            }
        }
        __syncthreads();
        scan256(count, offsets, wbuf);
        __builtin_amdgcn_s_waitcnt(0);   // drain this thread's offsets stores
        __syncthreads();                 // => all threads' stores drained
        if (tid == 0)                    // ONE release (single L2 writeback)
            __hip_atomic_store(flag, 1, __ATOMIC_RELEASE,
                               __HIP_MEMORY_SCOPE_AGENT);
    } else if (bid <= COUNT_BLOCKS) {
        // count: non-returning atomics (fire-and-forget, no per-lane wait)
        int e = (bid - 1) * 256 + tid;
        if (e < ET) {
            int dst = (e < E_EDGES) ? edge_dst[e] : (e - E_EDGES);
            atomicAdd(&count[dst], 1);
        }
        __builtin_amdgcn_s_waitcnt(0);   // atomic performed before done++
        __syncthreads();
        if (tid == 0)
            __hip_atomic_fetch_add(done, 1, __ATOMIC_RELAXED,
                                   __HIP_MEMORY_SCOPE_AGENT);
    } else if (bid < K2_SCAT0) {
        // layer-1 dual GEMM filler (independent of the sort chain)
        int t = bid - K2_GEMM0;
        dual_gemm_tile<IN_CH>(A, Wtl, Wtr, bl, br, Yl, Yr,
                              N_NODES, D1, t % G1X, t / G1X);
    } else {
        // scatter: wait for offsets, then place via cursor atomics
        if (tid == 0) {
            int guard = 0;
            while (aload(flag) == 0 && guard < (1 << 30)) {
                __builtin_amdgcn_s_sleep(8); guard++;
            }
        }
        __syncthreads();
        int e = (bid - K2_SCAT0) * 256 + tid;
        if (e < ET) {
            int dst = (e < E_EDGES) ? edge_dst[e] : (e - E_EDGES);
            int src = (e < E_EDGES) ? edge_src[e] : (e - E_EDGES);
            sorted_src[offsets[dst] + atomicAdd(&cursor[dst], 1)] = src;
        }
    }
}

// -------- K3: layer 1 aggregation (quarter-wave per edge, prefetch-2) -------

__global__ __launch_bounds__(256) void aggregate1_kernel(
        const unsigned char* __restrict__ xl1, const unsigned short* __restrict__ xr1,
        const float* __restrict__ att1, const float* __restrict__ bias1,
        const int* __restrict__ offsets, const int* __restrict__ sorted_src,
        unsigned short* __restrict__ x1) {
    int wave = threadIdx.x >> 6;
    int lane = threadIdx.x & 63;
    int q = lane >> 4;                 // quarter 0..3
    int ql = lane & 15;
    int dst = blockIdx.x * 4 + wave;
    if (dst >= M_PAD) return;
    int c0 = ql * 8;                   // channel index (8 ch/lane)
    if (dst >= N_NODES) {              // zero pad rows for the next GEMM
        if (q == 0) {
            uint4 z; z.x = z.y = z.z = z.w = 0;
            *(uint4*)(x1 + (size_t)dst * D1 + c0) = z;
        }
        return;
    }

    uint4 xu = *(const uint4*)(xr1 + (size_t)dst * D1 + c0);
    f32x2 xr[4] = {up2(xu.x), up2(xu.y), up2(xu.z), up2(xu.w)};
    float4 aa0 = *(const float4*)(att1 + c0);
    float4 aa1 = *(const float4*)(att1 + c0 + 4);
    f32x2 att[4];
    att[0].x = aa0.x * LOG2E; att[0].y = aa0.y * LOG2E;
    att[1].x = aa0.z * LOG2E; att[1].y = aa0.w * LOG2E;
    att[2].x = aa1.x * LOG2E; att[2].y = aa1.y * LOG2E;
    att[3].x = aa1.z * LOG2E; att[3].y = aa1.w * LOG2E;

    int beg = offsets[dst], end = offsets[dst + 1];
    const unsigned char* base = xl1 + c0;   // fp8: 1 byte/ch, row stride D1 B

    float l = 0.f;
    f32x2 acc[4] = {{0.f,0.f},{0.f,0.f},{0.f,0.f},{0.f,0.f}};

    int i = beg;
    int s0 = sorted_src[min(i + q, end - 1)];
    uint2 g0 = *(const uint2*)(base + (size_t)s0 * D1);
    bool more1 = (i + 4) < end;
    uint2 g1;
    if (more1) {
        int s1 = sorted_src[min(i + 4 + q, end - 1)];
        g1 = *(const uint2*)(base + (size_t)s1 * D1);
    }
    while (true) {
        bool more2 = (i + 8) < end;
        uint2 g2;
        if (more2) {
            int s2 = sorted_src[min(i + 8 + q, end - 1)];
            g2 = *(const uint2*)(base + (size_t)s2 * D1);
        }
        bool act = (i + q) < end;
        f32x2 v0 = f8up2<false>(g0.x), v1 = f8up2<true>(g0.x);
        f32x2 v2 = f8up2<false>(g0.y), v3 = f8up2<true>(g0.y);
        f32x2 p2 = att[0] * lrelu2(v0 + xr[0]);
        p2 += att[1] * lrelu2(v1 + xr[1]);
        p2 += att[2] * lrelu2(v2 + xr[2]);
        p2 += att[3] * lrelu2(v3 + xr[3]);
        float p = p2.x + p2.y;
        p += __shfl_xor(p, 1);          // head reduce (2 lanes/head)
        float w = act ? EXP2F(p) : 0.f;
        l += w;
        acc[0] += w * v0; acc[1] += w * v1; acc[2] += w * v2; acc[3] += w * v3;
        if (!more1) break;
        i += 4;
        g0 = g1; g1 = g2; more1 = more2;
    }
    // merge quarters
    l += __shfl_xor(l, 16);
    l += __shfl_xor(l, 32);
#pragma unroll
    for (int j = 0; j < 4; j++) {
        f32x2 t;
        t.x = __shfl_xor(acc[j].x, 16); t.y = __shfl_xor(acc[j].y, 16);
        acc[j] += t;
        t.x = __shfl_xor(acc[j].x, 32); t.y = __shfl_xor(acc[j].y, 32);
        acc[j] += t;
    }
    if (q == 0) {
        float inv = 1.f / l;
        float4 bb0 = *(const float4*)(bias1 + c0);
        float4 bb1 = *(const float4*)(bias1 + c0 + 4);
        unsigned short o[8];
        o[0] = f2b(fmaxf(acc[0].x * inv + bb0.x, 0.f));
        o[1] = f2b(fmaxf(acc[0].y * inv + bb0.y, 0.f));
        o[2] = f2b(fmaxf(acc[1].x * inv + bb0.z, 0.f));
        o[3] = f2b(fmaxf(acc[1].y * inv + bb0.w, 0.f));
        o[4] = f2b(fmaxf(acc[2].x * inv + bb1.x, 0.f));
        o[5] = f2b(fmaxf(acc[2].y * inv + bb1.y, 0.f));
        o[6] = f2b(fmaxf(acc[3].x * inv + bb1.z, 0.f));
        o[7] = f2b(fmaxf(acc[3].y * inv + bb1.w, 0.f));
        uint4 ov;
        ov.x = (unsigned int)o[0] | ((unsigned int)o[1] << 16);
        ov.y = (unsigned int)o[2] | ((unsigned int)o[3] << 16);
        ov.z = (unsigned int)o[4] | ((unsigned int)o[5] << 16);
        ov.w = (unsigned int)o[6] | ((unsigned int)o[7] << 16);
        *(uint4*)(x1 + (size_t)dst * D1 + c0) = ov;
    }
}

// ---- K4 gemm2: 32 cols/wave (16 MFMA per 4 A-loads); Yl fp8, Yr bf16 -------

template <int K>
__global__ __launch_bounds__(256) void dual_gemm_w32_kernel(
        const unsigned short* __restrict__ A,
        const unsigned short* __restrict__ Wtl,
        const unsigned short* __restrict__ Wtr,
        const float* __restrict__ bl, const float* __restrict__ br,
        unsigned char* __restrict__ Yl, unsigned short* __restrict__ Yr,
        int M, int NOUT) {
    const int NK = K / 32;
    int wave = threadIdx.x >> 6;
    int lane = threadIdx.x & 63;
    int row0 = blockIdx.x * 64;
    int col0 = blockIdx.y * 128 + wave * 32;
    int rsub = lane & 15;
    int koff = (lane >> 4) * 8;

    const unsigned short* ap = A + (size_t)(row0 + rsub) * K + koff;

    bf16x8 bfl[2][NK], bfr[2][NK];
#pragma unroll
    for (int c = 0; c < 2; c++) {
        const unsigned short* bpl = Wtl + (size_t)(col0 + c * 16 + rsub) * K + koff;
        const unsigned short* bpr = Wtr + (size_t)(col0 + c * 16 + rsub) * K + koff;
#pragma unroll
        for (int kb = 0; kb < NK; kb++) {
            bfl[c][kb] = *(const bf16x8*)(bpl + kb * 32);
            bfr[c][kb] = *(const bf16x8*)(bpr + kb * 32);
        }
    }

    f32x4 accl[2][4], accr[2][4];
#pragma unroll
    for (int c = 0; c < 2; c++)
#pragma unroll
        for (int t = 0; t < 4; t++) {
            accl[c][t] = (f32x4){0.f, 0.f, 0.f, 0.f};
            accr[c][t] = (f32x4){0.f, 0.f, 0.f, 0.f};
        }

#pragma unroll
    for (int kb = 0; kb < NK; kb++) {
        int off = kb * 32;
        bf16x8 a[4];
        a[0] = *(const bf16x8*)(ap + off);
        a[1] = *(const bf16x8*)(ap + 16 * K + off);
        a[2] = *(const bf16x8*)(ap + 32 * K + off);
        a[3] = *(const bf16x8*)(ap + 48 * K + off);
#pragma unroll
        for (int t = 0; t < 4; t++) {
#pragma unroll
            for (int c = 0; c < 2; c++) {
                accl[c][t] = __builtin_amdgcn_mfma_f32_16x16x32_bf16(
                    a[t], bfl[c][kb], accl[c][t], 0, 0, 0);
                accr[c][t] = __builtin_amdgcn_mfma_f32_16x16x32_bf16(
                    a[t], bfr[c][kb], accr[c][t], 0, 0, 0);
            }
        }
    }

    int rbase = row0 + (lane >> 4) * 4;
#pragma unroll
    for (int c = 0; c < 2; c++) {
        int colg = col0 + c * 16 + rsub;
        float bvl = bl[colg];
        float bvr = br[colg];
#pragma unroll
        for (int t = 0; t < 4; t++) {
#pragma unroll
            for (int r = 0; r < 4; r++) {
                int row = rbase + t * 16 + r;
                if (row < M) {
                    Yl[(size_t)row * NOUT + colg] = f2f8(accl[c][t][r] + bvl);
                    Yr[(size_t)row * NOUT + colg] = f2b(accr[c][t][r] + bvr);
                }
            }
        }
    }
}

// --- K5: fused layer-2 aggregation + classifier: one block per pair ---------

__global__ __launch_bounds__(256) void agg2_classifier_kernel(
        const unsigned char* __restrict__ xl2, const unsigned short* __restrict__ xr2,
        const float* __restrict__ att2, const float* __restrict__ bias2,
        const int* __restrict__ offsets, const int* __restrict__ sorted_src,
        const float* __restrict__ vanilla_x,
        const int* __restrict__ a1_raw, const int* __restrict__ a2_raw,
        const float* __restrict__ Wc, const float* __restrict__ bc,
        float* __restrict__ out) {
    __shared__ float x2row[2][D2];     // 2 KB
    __shared__ float mrg[2][32][9];    // 2.25 KB
    __shared__ float part[4];
    __shared__ int stride_s;
    int t = threadIdx.x;
    if (t < 64) {
        // int64 indices have zero odd words (values << 2^31); detect in parallel
        bool z = (t < 31) ? (a1_raw[1 + 2 * t] == 0) : true;
        unsigned long long m = __ballot(z);
        if (t == 0) stride_s = (m == ~0ull) ? 2 : 1;
    }
    __syncthreads();
    int stride = stride_s;
    int b = blockIdx.x;
    int a1 = a1_raw[(long)b * stride];
    int a2 = a2_raw[(long)b * stride];

    int wave = t >> 6;                 // 0..3
    int d = wave >> 1;                 // dst slot 0/1
    int ww = wave & 1;                 // wave within pair
    int lane = t & 63;
    int half = lane >> 5;
    int hl = lane & 31;
    int c0 = hl * 8;
    int dst = d ? a2 : a1;

    float xr[8], att[8];
    unpack8(*(const uint4*)(xr2 + (size_t)dst * D2 + c0), xr);
#pragma unroll
    for (int j = 0; j < 8; j++) att[j] = att2[c0 + j] * LOG2E;
    int beg = offsets[dst], end = offsets[dst + 1];
    const unsigned char* base = xl2 + c0;

    float l = 0.f;
    float acc[8];
#pragma unroll
    for (int j = 0; j < 8; j++) acc[j] = 0.f;

    int sub = 2 * ww + half;           // edge slot 0..3
    int i = beg;
    int s0 = sorted_src[min(i + sub, end - 1)];
    uint2 g0 = *(const uint2*)(base + (size_t)s0 * D2);
    bool more1 = (i + 4) < end;
    uint2 g1;
    if (more1) {
        int s1 = sorted_src[min(i + 4 + sub, end - 1)];
        g1 = *(const uint2*)(base + (size_t)s1 * D2);
    }
    while (true) {
        bool more2 = (i + 8) < end;
        uint2 g2;
        if (more2) {
            int s2 = sorted_src[min(i + 8 + sub, end - 1)];
            g2 = *(const uint2*)(base + (size_t)s2 * D2);
        }
        bool act = (i + sub) < end;
        float v[8];
        unpack8_f8(g0, v);
        float p = 0.f;
#pragma unroll
        for (int j = 0; j < 8; j++) p = fmaf(att[j], lrelu(v[j] + xr[j]), p);
        p += __shfl_xor(p, 1);
        p += __shfl_xor(p, 2);
        p += __shfl_xor(p, 4);
        p += __shfl_xor(p, 8);
        p += __shfl_xor(p, 16);
        float w = act ? EXP2F(p) : 0.f;
        l += w;
#pragma unroll
        for (int j = 0; j < 8; j++) acc[j] += w * v[j];
        if (!more1) break;
        i += 4;
        g0 = g1; g1 = g2; more1 = more2;
    }
    // merge halves within wave
    l += __shfl_xor(l, 32);
#pragma unroll
    for (int j = 0; j < 8; j++) acc[j] += __shfl_xor(acc[j], 32);
    // merge across the wave pair via LDS
    if (ww == 1 && half == 0) {
        mrg[d][hl][0] = l;
#pragma unroll
        for (int j = 0; j < 8; j++) mrg[d][hl][1 + j] = acc[j];
    }
    __syncthreads();
    if (ww == 0 && half == 0) {
        l += mrg[d][hl][0];
#pragma unroll
        for (int j = 0; j < 8; j++) acc[j] += mrg[d][hl][1 + j];
        float inv = 1.f / l;
#pragma unroll
        for (int j = 0; j < 8; j++)
            x2row[d][c0 + j] = acc[j] * inv + bias2[c0 + j];
    }
    __syncthreads();

    // classifier dot: thread t owns channel t of each of the 4 segments
    float s = vanilla_x[(size_t)a1 * IN_CH + t] * Wc[t]
            + vanilla_x[(size_t)a2 * IN_CH + t] * Wc[IN_CH + t]
            + x2row[0][t] * Wc[2 * IN_CH + t]
            + x2row[1][t] * Wc[3 * IN_CH + t];
    s += __shfl_xor(s, 1);
    s += __shfl_xor(s, 2);
    s += __shfl_xor(s, 4);
    s += __shfl_xor(s, 8);
    s += __shfl_xor(s, 16);
    s += __shfl_xor(s, 32);
    if (lane == 0) part[wave] = s;
    __syncthreads();
    if (t == 0) out[b] = part[0] + part[1] + part[2] + part[3] + bc[0];
}

// ---------------- launch ----------------

extern "C" void kernel_launch(void* const* d_in, const int* in_sizes, int n_in,
                              void* d_out, int out_size, void* d_ws, size_t ws_size,
                              hipStream_t stream) {
    const float* gnn_x     = (const float*)d_in[0];
    const float* vanilla_x = (const float*)d_in[1];
    const int*   edge_src  = (const int*)d_in[2];
    const int*   edge_dst  = (const int*)d_in[3];
    const int*   a1_idx    = (const int*)d_in[4];
    const int*   a2_idx    = (const int*)d_in[5];
    const float* Wl1   = (const float*)d_in[6];
    const float* bl1   = (const float*)d_in[7];
    const float* Wr1   = (const float*)d_in[8];
    const float* br1   = (const float*)d_in[9];
    const float* att1  = (const float*)d_in[10];
    const float* bias1 = (const float*)d_in[11];
    const float* Wl2   = (const float*)d_in[12];
    const float* bl2   = (const float*)d_in[13];
    const float* Wr2   = (const float*)d_in[14];
    const float* br2   = (const float*)d_in[15];
    const float* att2  = (const float*)d_in[16];
    const float* bias2 = (const float*)d_in[17];
    const float* Wc    = (const float*)d_in[18];
    const float* bc    = (const float*)d_in[19];
    float* out = (float*)d_out;

    // workspace layout (~42 MB)
    char* p = (char*)d_ws;
    unsigned short* xb   = (unsigned short*)p; p += (size_t)M_PAD * IN_CH * 2;
    unsigned short* x1b  = (unsigned short*)p; p += (size_t)M_PAD * D1 * 2;
    unsigned char*  xl1b = (unsigned char*)p;  p += (size_t)N_NODES * D1;      // fp8
    unsigned short* xr1b = (unsigned short*)p; p += (size_t)N_NODES * D1 * 2;
    unsigned char*  xl2b = (unsigned char*)p;  p += (size_t)N_NODES * D2;      // fp8
    unsigned short* xr2b = (unsigned short*)p; p += (size_t)N_NODES * D2 * 2;
    unsigned short* wt1l = (unsigned short*)p; p += (size_t)D1 * IN_CH * 2;
    unsigned short* wt1r = (unsigned short*)p; p += (size_t)D1 * IN_CH * 2;
    unsigned short* wt2l = (unsigned short*)p; p += (size_t)D2 * D1 * 2;
    unsigned short* wt2r = (unsigned short*)p; p += (size_t)D2 * D1 * 2;
    int* ibuf       = (int*)p; p += (size_t)40960 * 4;   // count/cursor/done/flag
    int* offsets    = (int*)p; p += (size_t)(N_NODES + 4) * 4;
    int* sorted_src = (int*)p; p += (size_t)ET * 4;
    int* count  = ibuf;                 // [20000]
    int* cursor = ibuf + 20032;         // [20000], 16B-aligned
    int* done   = ibuf + 40064;         // separate cacheline
    int* flag   = ibuf + 40128;         // separate cacheline

    // K1: zero(count/cursor/done/flag) + W^T transpose + x->bf16 convert
    prep_kernel<<<PREP_BLOCKS, 256, 0, stream>>>(
        gnn_x, Wl1, Wr1, Wl2, Wr2, xb, wt1l, wt1r, wt2l, wt2r, ibuf);

    // K2: count -> scan -> scatter chained via atomics, gemm1 overlapped
    sort_gemm1_kernel<<<K2_BLOCKS, 256, 0, stream>>>(
        edge_src, edge_dst, count, cursor, done, flag, offsets, sorted_src,
        xb, wt1l, wt1r, bl1, br1, xl1b, xr1b);

    // K3: layer-1 aggregation
    aggregate1_kernel<<<M_PAD / 4, 256, 0, stream>>>(
        xl1b, xr1b, att1, bias1, offsets, sorted_src, x1b);

    // K4: layer-2 dual GEMM (32 cols/wave)
    dim3 g2(M_PAD / 64, D2 / 128);   // (313, 2)
    dual_gemm_w32_kernel<D1><<<g2, 256, 0, stream>>>(
        x1b, wt2l, wt2r, bl2, br2, xl2b, xr2b, N_NODES, D2);

    // K5: fused layer-2 aggregation + classifier (one block per pair)
    agg2_classifier_kernel<<<BPAIRS, 256, 0, stream>>>(
        xl2b, xr2b, att2, bias2, offsets, sorted_src,
        vanilla_x, a1_idx, a2_idx, Wc, bc, out);
}